// Round 4
// baseline (2705.119 us; speedup 1.0000x reference)
//
#include <hip/hip_runtime.h>
#include <math.h>

#define T_SEQ   1024
#define BATCH   2
#define CDIM    1024
#define NHEAD   16
#define VHEAD   32
#define NOPE_D  32
#define ROPED   64
#define KEEP    256
#define HEAD_D  96   // NOPE + ROPE
#define SCALE_ATTN 0.1020620726159658f  // 1/sqrt(96)

// flash tile params
#define BQ   64     // queries per block (512 threads)
#define BKT  64     // keys per tile
#define SK   100    // Q/K LDS row stride (floats): mult of 4, <=2-way on b128
#define SPT  66     // Pt row stride [k][q]
#define SPV  36     // V LDS row stride

// GEMM v3 tile params: 128x128, 8x8 micro (split 4+4 at +64), double-buffered
#define GBK 16
#define SA  132     // padded row stride: 132%32=4 -> <=2-way (free)

// fused buffer strides
#define XPW   192   // xp: [0:96) nq | [96:160) kro | [160:192) ckv
#define QPW  1536   // qp: [0:512) qn | [512:1536) qr
#define KVW  1024   // kvp: [0:512) kn | [512:1024) v1
#define WKW  2048   // wkv: [0:1536) kw | [1536:2048) vw
#define SKW  2048   // skv: [0:1536) ks | [1536:2048) vs

// ---------------------------------------------------------------------------
// fp32 GEMM v3: C[M,N] = A[M,K] @ B[K,N] with row strides lda/ldb/ldc.
// 128x128 block, 256 threads, 8x8 micro-tile, double-buffered LDS,
// one barrier per K-step. Requires K%16==0, N%4==0 (all call sites satisfy).
// ---------------------------------------------------------------------------
__global__ __launch_bounds__(256, 2) void gemm_db(const float* __restrict__ A,
                                                  const float* __restrict__ B,
                                                  float* __restrict__ C,
                                                  int M, int N, int K,
                                                  int lda, int ldb, int ldc) {
    __shared__ float As[2][GBK][SA];   // [buf][k][m] transposed A tile
    __shared__ float Bs[2][GBK][SA];   // [buf][k][n]
    int t = threadIdx.x;
    int tx = t & 15, ty = t >> 4;
    int row0 = blockIdx.y * 128, col0 = blockIdx.x * 128;
    float acc[8][8] = {};
    float4 ra[2], rb[2];

    auto load_step = [&](int s) {
        int k0 = s * GBK;
#pragma unroll
        for (int r = 0; r < 2; ++r) {
            int idx = t + 256 * r;            // 0..511
            int row = idx >> 2, k4 = idx & 3;
            int gr = row0 + row;
            ra[r] = make_float4(0.f, 0.f, 0.f, 0.f);
            if (gr < M) ra[r] = *(const float4*)&A[(size_t)gr * lda + k0 + k4 * 4];
        }
#pragma unroll
        for (int r = 0; r < 2; ++r) {
            int idx = t + 256 * r;
            int kk = idx >> 5, n4 = idx & 31;
            int gc = col0 + n4 * 4;
            rb[r] = make_float4(0.f, 0.f, 0.f, 0.f);
            if (gc + 3 < N) rb[r] = *(const float4*)&B[(size_t)(k0 + kk) * ldb + gc];
        }
    };
    auto store_step = [&](int bufi) {
#pragma unroll
        for (int r = 0; r < 2; ++r) {
            int idx = t + 256 * r;
            int row = idx >> 2, k4 = idx & 3;
            As[bufi][k4 * 4 + 0][row] = ra[r].x;
            As[bufi][k4 * 4 + 1][row] = ra[r].y;
            As[bufi][k4 * 4 + 2][row] = ra[r].z;
            As[bufi][k4 * 4 + 3][row] = ra[r].w;
        }
#pragma unroll
        for (int r = 0; r < 2; ++r) {
            int idx = t + 256 * r;
            int kk = idx >> 5, n4 = idx & 31;
            *(float4*)&Bs[bufi][kk][n4 * 4] = rb[r];
        }
    };

    load_step(0);
    store_step(0);
    __syncthreads();
    int nsteps = K / GBK;
    for (int s = 0; s < nsteps; ++s) {
        int cur = s & 1;
        if (s + 1 < nsteps) load_step(s + 1);   // global latency hides under compute
#pragma unroll
        for (int kk = 0; kk < GBK; ++kk) {
            float4 a0 = *(float4*)&As[cur][kk][ty * 4];
            float4 a1 = *(float4*)&As[cur][kk][64 + ty * 4];
            float4 b0 = *(float4*)&Bs[cur][kk][tx * 4];
            float4 b1 = *(float4*)&Bs[cur][kk][64 + tx * 4];
            float av[8] = {a0.x, a0.y, a0.z, a0.w, a1.x, a1.y, a1.z, a1.w};
            float bv[8] = {b0.x, b0.y, b0.z, b0.w, b1.x, b1.y, b1.z, b1.w};
#pragma unroll
            for (int i = 0; i < 8; i++)
#pragma unroll
                for (int j = 0; j < 8; j++) acc[i][j] += av[i] * bv[j];
        }
        if (s + 1 < nsteps) {
            store_step(cur ^ 1);   // other buffer: safe before others finish reading cur
            __syncthreads();
        }
    }

#pragma unroll
    for (int i = 0; i < 8; i++) {
        int gr = row0 + ((i < 4) ? (ty * 4 + i) : (64 + ty * 4 + i - 4));
        if (gr >= M) continue;
        int gc0 = col0 + tx * 4;
        if (gc0 + 3 < N)
            *(float4*)&C[(size_t)gr * ldc + gc0] =
                make_float4(acc[i][0], acc[i][1], acc[i][2], acc[i][3]);
        int gc1 = col0 + 64 + tx * 4;
        if (gc1 + 3 < N)
            *(float4*)&C[(size_t)gr * ldc + gc1] =
                make_float4(acc[i][4], acc[i][5], acc[i][6], acc[i][7]);
    }
}

// ---------------------------------------------------------------------------
// pack up to 3 weight matrices column-wise: dst[r][.] = [s0[r]|s1[r]|s2[r]]
__global__ void pack3(float* __restrict__ dst,
                      const float* __restrict__ s0, int w0,
                      const float* __restrict__ s1, int w1,
                      const float* __restrict__ s2, int w2, int rows) {
    int W = w0 + w1 + w2;
    int r = blockIdx.x;
    if (r >= rows) return;
    for (int c = threadIdx.x; c < W; c += blockDim.x) {
        float v;
        if (c < w0) v = s0[(size_t)r * w0 + c];
        else if (c < w0 + w1) v = s1[(size_t)r * w1 + (c - w0)];
        else v = s2[(size_t)r * w2 + (c - w0 - w1)];
        dst[(size_t)r * W + c] = v;
    }
}

// ---------------------------------------------------------------------------
__global__ void rms_rows(float* __restrict__ buf, const float* __restrict__ g,
                         int D, int stride) {
    int row = blockIdx.x;
    int lane = threadIdx.x;  // blockDim = 64
    float* rp = buf + (size_t)row * stride;
    float ss = 0.f;
    for (int d = lane; d < D; d += 64) {
        float v = rp[d];
        ss += v * v;
    }
    for (int off = 32; off; off >>= 1) ss += __shfl_xor(ss, off, 64);
    float r = rsqrtf(ss / (float)D + 1e-6f);
    for (int d = lane; d < D; d += 64) rp[d] *= r * g[d];
}

// ---------------------------------------------------------------------------
__global__ void rope_inplace(float* __restrict__ buf, int nrows, int rstride,
                             int nheads, int hstride, int roff, int posmod,
                             float scale) {
    int total = nrows * nheads * 32;
    for (int it = blockIdx.x * blockDim.x + threadIdx.x; it < total;
         it += gridDim.x * blockDim.x) {
        int i = it & 31;
        int hr = it >> 5;
        int h = hr % nheads;
        int row = hr / nheads;
        int pos = row % posmod;
        float expo = (float)i * (1.0f / 32.0f);
        float f = 1.0f / powf(10000.0f, expo);
        float a = (float)pos * f;
        float s, c;
        sincosf(a, &s, &c);
        size_t base = (size_t)row * rstride + (size_t)h * hstride + roff;
        float v1 = buf[base + i], v2 = buf[base + 32 + i];
        buf[base + i]      = (v1 * c - v2 * s) * scale;
        buf[base + 32 + i] = (v1 * s + v2 * c) * scale;
    }
}

// ---------------------------------------------------------------------------
__global__ void scores_gate(const float* __restrict__ x,
                            const float* __restrict__ w_imp,
                            const float* __restrict__ w_gate,
                            float* __restrict__ scores,
                            float* __restrict__ gate_raw) {
    int wid = (blockIdx.x * blockDim.x + threadIdx.x) >> 6;
    int lane = threadIdx.x & 63;
    if (wid >= BATCH * T_SEQ) return;
    int b = wid >> 10;
    const float* xr = x + (size_t)wid * CDIM;
    float s0 = 0, g0 = 0, g1 = 0, g2 = 0;
    for (int c = lane; c < CDIM; c += 64) {
        float xv = xr[c];
        s0 += xv * w_imp[c];
        g0 += xv * w_gate[c * 3 + 0];
        g1 += xv * w_gate[c * 3 + 1];
        g2 += xv * w_gate[c * 3 + 2];
    }
    for (int off = 32; off; off >>= 1) {
        s0 += __shfl_xor(s0, off, 64);
        g0 += __shfl_xor(g0, off, 64);
        g1 += __shfl_xor(g1, off, 64);
        g2 += __shfl_xor(g2, off, 64);
    }
    if (lane == 0) {
        scores[wid] = s0;
        atomicAdd(&gate_raw[b * 3 + 0], g0);
        atomicAdd(&gate_raw[b * 3 + 1], g1);
        atomicAdd(&gate_raw[b * 3 + 2], g2);
    }
}

__global__ void gate_final(const float* __restrict__ gate_raw, float* __restrict__ gate) {
    int b = threadIdx.x;
    if (b >= BATCH) return;
    float v0 = gate_raw[b * 3 + 0] / (float)T_SEQ;
    float v1 = gate_raw[b * 3 + 1] / (float)T_SEQ;
    float v2 = gate_raw[b * 3 + 2] / (float)T_SEQ;
    float m = fmaxf(v0, fmaxf(v1, v2));
    float e0 = expf(v0 - m), e1 = expf(v1 - m), e2 = expf(v2 - m);
    float s = e0 + e1 + e2;
    gate[b * 3 + 0] = e0 / s;
    gate[b * 3 + 1] = e1 / s;
    gate[b * 3 + 2] = e2 / s;
}

// ---------------------------------------------------------------------------
__global__ void topk_kernel(const float* __restrict__ scores, int* __restrict__ idx) {
    int b = blockIdx.x;
    __shared__ float s[1024];
    __shared__ int ps[1024];
    int t = threadIdx.x;
    s[t] = scores[b * T_SEQ + t];
    __syncthreads();
    float mine = s[t];
    int rank = 0;
    for (int j = 0; j < 1024; j++) {
        float v = s[j];
        rank += (v > mine) || (v == mine && j < t);
    }
    int selv = (rank < KEEP) ? 1 : 0;
    ps[t] = selv;
    __syncthreads();
    for (int off = 1; off < 1024; off <<= 1) {
        int add = (t >= off) ? ps[t - off] : 0;
        __syncthreads();
        ps[t] += add;
        __syncthreads();
    }
    if (selv) idx[b * KEEP + ps[t] - 1] = t;
}

__global__ void gather_sel(const float* __restrict__ x, const int* __restrict__ idx,
                           float* __restrict__ sel) {
    for (size_t i = (size_t)blockIdx.x * blockDim.x + threadIdx.x;
         i < (size_t)BATCH * KEEP * CDIM; i += (size_t)gridDim.x * blockDim.x) {
        int c = (int)(i & (CDIM - 1));
        int r = (int)((i >> 10) & (KEEP - 1));
        int b = (int)(i >> 18);
        sel[i] = x[((size_t)b * T_SEQ + idx[b * KEEP + r]) * CDIM + c];
    }
}

// ---------------------------------------------------------------------------
// Fused 3-branch flash attention v4 (measured-best structure), reading the
// fused/strided buffers: qp (QPW), kvp (KVW), xp (XPW, kro at +96),
// skv (SKW), wkv (WKW).
// Grid: (T/64, NHEAD, BATCH), 512 threads. LDS = 78.3 KB -> 2 blocks/CU.
// ---------------------------------------------------------------------------
__global__ __launch_bounds__(512, 4) void flash_fused(
    const float* __restrict__ qp, const float* __restrict__ kvp,
    const float* __restrict__ xp, const float* __restrict__ skv,
    const float* __restrict__ wkv, const float* __restrict__ gate,
    float* __restrict__ out) {
    __shared__ float Qs[BQ * SK];    // 64 x 96 (stride 100)
    __shared__ float Ks[BKT * SK];   // 64 x 96 (stride 100)
    __shared__ float Vs[BKT * SPV];  // 64 x 32 (stride 36)
    __shared__ float Pt[BKT * SPT];  // [k][q] (stride 66)
    __shared__ float mrow[BQ], lrow[BQ], arow[BQ], mtil[BQ];

    int b = blockIdx.z, h = blockIdx.y;
    int qt = blockIdx.x;
    if (b == 1) qt = (gridDim.x - 1) - qt;   // balance causal cost across z-pairs
    int q0 = qt * BQ;
    int t = threadIdx.x;
    int tq = t >> 4, tk = t & 15;   // S mapping: q=2*tq+i, k=16*j+tk
    int qg = t >> 4, dg = t & 15;   // PV mapping: q=2*qg+i, d=2*dg+j

    // stage Q tile (64 rows x 24 float4)
    for (int i = t; i < BQ * 24; i += 512) {
        int row = i / 24, d4 = i % 24;
        size_t rq = (size_t)b * T_SEQ + q0 + row;
        float4 v;
        if (d4 < 8) v = *(const float4*)&qp[rq * QPW + h * 32 + d4 * 4];
        else        v = *(const float4*)&qp[rq * QPW + 512 + h * 64 + (d4 - 8) * 4];
        *(float4*)&Qs[row * SK + d4 * 4] = v;
    }

    float comb[2][2] = {};
    for (int phase = 0; phase < 3; phase++) {
        bool causal = (phase != 1);
        int ntiles = causal ? (qt + 1) : (KEEP / BKT);
        float o00 = 0.f, o01 = 0.f, o10 = 0.f, o11 = 0.f;
        __syncthreads();   // previous phase readers of lrow done
        if (t < BQ) { mrow[t] = -1e30f; lrow[t] = 0.f; }

        for (int kt = 0; kt < ntiles; kt++) {
            int j0 = kt * BKT;
            __syncthreads();  // previous tile readers of Ks/Vs/Pt done

            // stage K tile (64 rows x 24 float4)
            for (int i = t; i < BKT * 24; i += 512) {
                int row = i / 24, d4 = i % 24;
                int j = j0 + row;
                float4 v;
                if (phase == 0) {
                    size_t rk = (size_t)b * T_SEQ + j;
                    if (d4 < 8) v = *(const float4*)&kvp[rk * KVW + h * 32 + d4 * 4];
                    else        v = *(const float4*)&xp[rk * XPW + 96 + (d4 - 8) * 4];
                } else if (phase == 1) {
                    v = *(const float4*)&skv[((size_t)b * KEEP + j) * SKW + h * 96 + d4 * 4];
                } else {
                    v = *(const float4*)&wkv[((size_t)b * T_SEQ + j) * WKW + h * 96 + d4 * 4];
                }
                *(float4*)&Ks[row * SK + d4 * 4] = v;
            }
            // stage V tile (64 rows x 8 float4)
            for (int i = t; i < BKT * 8; i += 512) {
                int row = i >> 3, d4 = i & 7;
                int j = j0 + row;
                float4 v;
                if (phase == 0)      v = *(const float4*)&kvp[((size_t)b * T_SEQ + j) * KVW + 512 + h * 32 + d4 * 4];
                else if (phase == 1) v = *(const float4*)&skv[((size_t)b * KEEP  + j) * SKW + 1536 + h * 32 + d4 * 4];
                else                 v = *(const float4*)&wkv[((size_t)b * T_SEQ + j) * WKW + 1536 + h * 32 + d4 * 4];
                *(float4*)&Vs[row * SPV + d4 * 4] = v;
            }
            __syncthreads();

            // S = Q.K^T  (2q x 4k per thread)
            float s[2][4] = {};
#pragma unroll 6
            for (int d = 0; d < HEAD_D; d += 4) {
                float4 qa = *(float4*)&Qs[(2 * tq)     * SK + d];
                float4 qb = *(float4*)&Qs[(2 * tq + 1) * SK + d];
#pragma unroll
                for (int j = 0; j < 4; j++) {
                    float4 kv = *(float4*)&Ks[(16 * j + tk) * SK + d];
                    s[0][j] += qa.x * kv.x + qa.y * kv.y + qa.z * kv.z + qa.w * kv.w;
                    s[1][j] += qb.x * kv.x + qb.y * kv.y + qb.z * kv.z + qb.w * kv.w;
                }
            }
#pragma unroll
            for (int i = 0; i < 2; i++)
#pragma unroll
                for (int j = 0; j < 4; j++) {
                    int qq = q0 + 2 * tq + i;
                    int kk = j0 + 16 * j + tk;
                    float sv = s[i][j] * SCALE_ATTN;
                    if (causal && kk > qq) sv = -1e30f;
                    Pt[(16 * j + tk) * SPT + (2 * tq + i)] = sv;
                }
            __syncthreads();

            // tile row-max: q = t>>3, 8 lanes per row
            {
                int q = t >> 3, sub = t & 7;
                float mt = -1e30f;
#pragma unroll
                for (int i2 = 0; i2 < 8; i2++)
                    mt = fmaxf(mt, Pt[(sub * 8 + i2) * SPT + q]);
                mt = fmaxf(mt, __shfl_xor(mt, 1, 64));
                mt = fmaxf(mt, __shfl_xor(mt, 2, 64));
                mt = fmaxf(mt, __shfl_xor(mt, 4, 64));
                if (sub == 0) mtil[q] = mt;
            }
            __syncthreads();
            if (t < BQ) {
                float mnew = fmaxf(mrow[t], mtil[t]);
                arow[t] = __expf(mrow[t] - mnew);
                mrow[t] = mnew;
            }
            __syncthreads();
            // exponentiate + row sums
            {
                int q = t >> 3, sub = t & 7;
                float mnew = mrow[q];
                float psum = 0.f;
#pragma unroll
                for (int i2 = 0; i2 < 8; i2++) {
                    int kk = sub * 8 + i2;
                    float p = __expf(Pt[kk * SPT + q] - mnew);
                    Pt[kk * SPT + q] = p;
                    psum += p;
                }
                psum += __shfl_xor(psum, 1, 64);
                psum += __shfl_xor(psum, 2, 64);
                psum += __shfl_xor(psum, 4, 64);
                if (sub == 0) lrow[q] = lrow[q] * arow[q] + psum;
            }
            __syncthreads();

            // O accumulate (2q x 2d per thread)
            {
                float a0 = arow[2 * qg], a1 = arow[2 * qg + 1];
                o00 *= a0; o01 *= a0; o10 *= a1; o11 *= a1;
#pragma unroll 8
                for (int kk = 0; kk < BKT; kk++) {
                    float2 pv = *(float2*)&Pt[kk * SPT + 2 * qg];
                    float2 vv = *(float2*)&Vs[kk * SPV + 2 * dg];
                    o00 += pv.x * vv.x; o01 += pv.x * vv.y;
                    o10 += pv.y * vv.x; o11 += pv.y * vv.y;
                }
            }
        }  // key tiles

        // gate combine
        {
            float g = gate[b * 3 + phase];
            float i0 = g / lrow[2 * qg], i1 = g / lrow[2 * qg + 1];
            comb[0][0] += o00 * i0; comb[0][1] += o01 * i0;
            comb[1][0] += o10 * i1; comb[1][1] += o11 * i1;
        }
    }  // phases

    size_t r0 = ((size_t)b * T_SEQ + q0 + 2 * qg) * 512 + h * 32 + 2 * dg;
    out[r0]           = comb[0][0];
    out[r0 + 1]       = comb[0][1];
    out[r0 + 512]     = comb[1][0];
    out[r0 + 512 + 1] = comb[1][1];
}

// ---------------------------------------------------------------------------
extern "C" void kernel_launch(void* const* d_in, const int* in_sizes, int n_in,
                              void* d_out, int out_size, void* d_ws, size_t ws_size,
                              hipStream_t stream) {
    const float* x        = (const float*)d_in[0];
    const float* w_cq     = (const float*)d_in[1];
    const float* g_qnorm  = (const float*)d_in[2];
    const float* w_dqn    = (const float*)d_in[3];
    const float* w_dqr    = (const float*)d_in[4];
    const float* w_ckv    = (const float*)d_in[5];
    const float* g_kvnorm = (const float*)d_in[6];
    const float* w_dkn    = (const float*)d_in[7];
    const float* w_dv     = (const float*)d_in[8];
    const float* w_krope  = (const float*)d_in[9];
    const float* w_imp    = (const float*)d_in[10];
    const float* w_selk   = (const float*)d_in[11];
    const float* w_selv   = (const float*)d_in[12];
    const float* w_wink   = (const float*)d_in[13];
    const float* w_winv   = (const float*)d_in[14];
    const float* w_gate   = (const float*)d_in[15];
    const float* w_proj   = (const float*)d_in[16];
    float* out = (float*)d_out;

    const int BT = BATCH * T_SEQ;  // 2048
    const int BS = BATCH * KEEP;   // 512

    float* ws = (float*)d_ws;
    size_t o = 0;
    float* xp     = ws + o; o += (size_t)BT * XPW;
    float* qp     = ws + o; o += (size_t)BT * QPW;
    float* kvp    = ws + o; o += (size_t)BT * KVW;
    float* wkv    = ws + o; o += (size_t)BT * WKW;
    float* skv    = ws + o; o += (size_t)BS * SKW;
    float* selb   = ws + o; o += (size_t)BS * CDIM;
    float* attn   = ws + o; o += (size_t)BT * 512;
    float* Bsm    = ws + o; o += (size_t)1024 * XPW;
    float* Bq     = ws + o; o += (size_t)96 * QPW;
    float* Bkv    = ws + o; o += (size_t)32 * KVW;
    float* Bw     = ws + o; o += (size_t)1024 * WKW;
    float* Bsel   = ws + o; o += (size_t)1024 * SKW;
    float* scores = ws + o; o += 2048;
    float* gateraw= ws + o; o += 8;
    float* gatef  = ws + o; o += 8;
    int*   idx    = (int*)(ws + o); o += 512;

    hipMemsetAsync(gateraw, 0, 8 * sizeof(float), stream);

    auto gemm = [&](const float* A, const float* Bm, float* C, int M, int N, int K,
                    int lda, int ldb, int ldc) {
        dim3 grid((N + 127) / 128, (M + 127) / 128);
        gemm_db<<<grid, 256, 0, stream>>>(A, Bm, C, M, N, K, lda, ldb, ldc);
    };

    // weight packs (all independent)
    pack3<<<1024, 256, 0, stream>>>(Bsm, w_cq, 96, w_krope, 64, w_ckv, 32, 1024);
    pack3<<<96,   256, 0, stream>>>(Bq, w_dqn, 512, w_dqr, 1024, w_dqn, 0, 96);
    pack3<<<32,   256, 0, stream>>>(Bkv, w_dkn, 512, w_dv, 512, w_dkn, 0, 32);
    pack3<<<1024, 256, 0, stream>>>(Bw, w_wink, 1536, w_winv, 512, w_wink, 0, 1024);
    pack3<<<1024, 256, 0, stream>>>(Bsel, w_selk, 1536, w_selv, 512, w_selk, 0, 1024);

    // fused projections off x: xp = x @ [w_cq | w_krope | w_ckv]
    gemm(x, Bsm, xp, BT, XPW, CDIM, CDIM, XPW, XPW);
    rms_rows<<<BT, 64, 0, stream>>>(xp, g_qnorm, 96, XPW);          // nq  = xp[:,0:96]
    rms_rows<<<BT, 64, 0, stream>>>(xp + 160, g_kvnorm, 32, XPW);   // ckv = xp[:,160:192]
    rope_inplace<<<256, 256, 0, stream>>>(xp, BT, XPW, 1, 0, 96, T_SEQ, 1.0f / NHEAD); // kro

    // q projections: qp = nq @ [w_dqn | w_dqr]
    gemm(xp, Bq, qp, BT, QPW, 96, XPW, QPW, QPW);
    rope_inplace<<<2048, 256, 0, stream>>>(qp, BT, QPW, 16, 64, 512, T_SEQ, 1.0f);

    // kv projections: kvp = ckv @ [w_dkn | w_dv]
    gemm(xp + 160, Bkv, kvp, BT, KVW, 32, XPW, KVW, KVW);

    // window k/v: wkv = x @ [w_wink | w_winv]
    gemm(x, Bw, wkv, BT, WKW, CDIM, CDIM, WKW, WKW);
    rope_inplace<<<2048, 256, 0, stream>>>(wkv, BT, WKW, 16, 96, 32, T_SEQ, 1.0f);

    // scores + gate
    scores_gate<<<(BT * 64 + 255) / 256, 256, 0, stream>>>(x, w_imp, w_gate, scores, gateraw);
    gate_final<<<1, 64, 0, stream>>>(gateraw, gatef);

    // top-k select + selected k/v: skv = sel @ [w_selk | w_selv]
    topk_kernel<<<BATCH, 1024, 0, stream>>>(scores, idx);
    gather_sel<<<2048, 256, 0, stream>>>(x, idx, selb);
    gemm(selb, Bsel, skv, BS, SKW, CDIM, CDIM, SKW, SKW);
    rope_inplace<<<512, 256, 0, stream>>>(skv, BS, SKW, 16, 96, 32, KEEP, 1.0f);

    // fused attention
    dim3 fgrid(T_SEQ / BQ, NHEAD, BATCH);
    flash_fused<<<fgrid, 512, 0, stream>>>(qp, kvp, xp, skv, wkv, gatef, attn);

    // output projection (no pack: single B)
    gemm(attn, w_proj, out, BT, CDIM, 512, 512, CDIM, CDIM);
}

// Round 5
// 1271.828 us; speedup vs baseline: 2.1270x; 2.1270x over previous
//
#include <hip/hip_runtime.h>
#include <math.h>

#define T_SEQ   1024
#define BATCH   2
#define CDIM    1024
#define NHEAD   16
#define VHEAD   32
#define NOPE_D  32
#define ROPED   64
#define KEEP    256
#define HEAD_D  96   // NOPE + ROPE
#define SCALE_ATTN 0.1020620726159658f  // 1/sqrt(96)

// flash tile params
#define BQ   64     // queries per block (512 threads)
#define BKT  64     // keys per tile
#define SK   100    // Q/K LDS row stride (floats): mult of 4, <=2-way on b128
#define SPT  66     // Pt row stride [k][q]
#define SPV  36     // V LDS row stride

// GEMM tile params: 128x128 block, 8x8 micro, single-buffered (spill-safe)
#define GBK 16
#define SA  132     // padded row stride: 132%32=4 -> <=2-way (free)

// fused buffer strides
#define XPW   192   // xp: [0:96) nq | [96:160) kro | [160:192) ckv
#define QPW  1536   // qp: [0:512) qn | [512:1536) qr
#define KVW  1024   // kvp: [0:512) kn | [512:1024) v1
#define WKW  2048   // wkv: [0:1536) kw | [1536:2048) vw
#define SKW  2048   // skv: [0:1536) ks | [1536:2048) vs

// ---------------------------------------------------------------------------
// fp32 GEMM v4: C[M,N] = A[M,K] @ B[K,N] with row strides lda/ldb/ldc.
// 128x128 block, 256 threads, 8x8 micro-tile (split 4+4 at +64), single
// LDS buffer, 2 barriers/step. ~95 VGPR -> no spill, 4 waves/SIMD.
// Requires K%16==0; M,N guarded (N%4==0 at all call sites).
// ---------------------------------------------------------------------------
__global__ __launch_bounds__(256) void gemm128(const float* __restrict__ A,
                                               const float* __restrict__ B,
                                               float* __restrict__ C,
                                               int M, int N, int K,
                                               int lda, int ldb, int ldc) {
    __shared__ float As[GBK][SA];   // [k][m] transposed A tile
    __shared__ float Bs[GBK][SA];   // [k][n]
    int t = threadIdx.x;
    int tx = t & 15, ty = t >> 4;
    int row0 = blockIdx.y * 128, col0 = blockIdx.x * 128;
    float acc[8][8] = {};

    for (int k0 = 0; k0 < K; k0 += GBK) {
        // stage A: 128 rows x 16 k = 512 float4, 2 per thread, store transposed
#pragma unroll
        for (int r = 0; r < 2; r++) {
            int idx = t + 256 * r;            // 0..511
            int row = idx >> 2, k4 = idx & 3;
            int gr = row0 + row;
            float4 v = make_float4(0.f, 0.f, 0.f, 0.f);
            if (gr < M) v = *(const float4*)&A[(size_t)gr * lda + k0 + k4 * 4];
            As[k4 * 4 + 0][row] = v.x;
            As[k4 * 4 + 1][row] = v.y;
            As[k4 * 4 + 2][row] = v.z;
            As[k4 * 4 + 3][row] = v.w;
        }
        // stage B: 16 k x 128 n = 512 float4, 2 per thread
#pragma unroll
        for (int r = 0; r < 2; r++) {
            int idx = t + 256 * r;
            int kk = idx >> 5, n4 = idx & 31;
            int gc = col0 + n4 * 4;
            float4 v = make_float4(0.f, 0.f, 0.f, 0.f);
            if (gc + 3 < N) {
                v = *(const float4*)&B[(size_t)(k0 + kk) * ldb + gc];
            } else if (gc < N) {
                const float* bp = &B[(size_t)(k0 + kk) * ldb];
                float tmp[4] = {0.f, 0.f, 0.f, 0.f};
                for (int j = 0; j < 4 && gc + j < N; j++) tmp[j] = bp[gc + j];
                v = make_float4(tmp[0], tmp[1], tmp[2], tmp[3]);
            }
            *(float4*)&Bs[kk][n4 * 4] = v;
        }
        __syncthreads();
#pragma unroll
        for (int kk = 0; kk < GBK; kk++) {
            float4 a0 = *(float4*)&As[kk][ty * 4];
            float4 a1 = *(float4*)&As[kk][64 + ty * 4];
            float4 b0 = *(float4*)&Bs[kk][tx * 4];
            float4 b1 = *(float4*)&Bs[kk][64 + tx * 4];
            float av[8] = {a0.x, a0.y, a0.z, a0.w, a1.x, a1.y, a1.z, a1.w};
            float bv[8] = {b0.x, b0.y, b0.z, b0.w, b1.x, b1.y, b1.z, b1.w};
#pragma unroll
            for (int i = 0; i < 8; i++)
#pragma unroll
                for (int j = 0; j < 8; j++) acc[i][j] += av[i] * bv[j];
        }
        __syncthreads();
    }

#pragma unroll
    for (int i = 0; i < 8; i++) {
        int gr = row0 + ((i < 4) ? (ty * 4 + i) : (64 + ty * 4 + (i - 4)));
        if (gr >= M) continue;
        int gc0 = col0 + tx * 4;
        if (gc0 + 3 < N)
            *(float4*)&C[(size_t)gr * ldc + gc0] =
                make_float4(acc[i][0], acc[i][1], acc[i][2], acc[i][3]);
        int gc1 = col0 + 64 + tx * 4;
        if (gc1 + 3 < N)
            *(float4*)&C[(size_t)gr * ldc + gc1] =
                make_float4(acc[i][4], acc[i][5], acc[i][6], acc[i][7]);
    }
}

// ---------------------------------------------------------------------------
// pack up to 3 weight matrices column-wise: dst[r][.] = [s0[r]|s1[r]|s2[r]]
__global__ void pack3(float* __restrict__ dst,
                      const float* __restrict__ s0, int w0,
                      const float* __restrict__ s1, int w1,
                      const float* __restrict__ s2, int w2, int rows) {
    int W = w0 + w1 + w2;
    int r = blockIdx.x;
    if (r >= rows) return;
    for (int c = threadIdx.x; c < W; c += blockDim.x) {
        float v;
        if (c < w0) v = s0[(size_t)r * w0 + c];
        else if (c < w0 + w1) v = s1[(size_t)r * w1 + (c - w0)];
        else v = s2[(size_t)r * w2 + (c - w0 - w1)];
        dst[(size_t)r * W + c] = v;
    }
}

// ---------------------------------------------------------------------------
__global__ void rms_rows(float* __restrict__ buf, const float* __restrict__ g,
                         int D, int stride) {
    int row = blockIdx.x;
    int lane = threadIdx.x;  // blockDim = 64
    float* rp = buf + (size_t)row * stride;
    float ss = 0.f;
    for (int d = lane; d < D; d += 64) {
        float v = rp[d];
        ss += v * v;
    }
    for (int off = 32; off; off >>= 1) ss += __shfl_xor(ss, off, 64);
    float r = rsqrtf(ss / (float)D + 1e-6f);
    for (int d = lane; d < D; d += 64) rp[d] *= r * g[d];
}

// ---------------------------------------------------------------------------
__global__ void rope_inplace(float* __restrict__ buf, int nrows, int rstride,
                             int nheads, int hstride, int roff, int posmod,
                             float scale) {
    int total = nrows * nheads * 32;
    for (int it = blockIdx.x * blockDim.x + threadIdx.x; it < total;
         it += gridDim.x * blockDim.x) {
        int i = it & 31;
        int hr = it >> 5;
        int h = hr % nheads;
        int row = hr / nheads;
        int pos = row % posmod;
        float expo = (float)i * (1.0f / 32.0f);
        float f = 1.0f / powf(10000.0f, expo);
        float a = (float)pos * f;
        float s, c;
        sincosf(a, &s, &c);
        size_t base = (size_t)row * rstride + (size_t)h * hstride + roff;
        float v1 = buf[base + i], v2 = buf[base + 32 + i];
        buf[base + i]      = (v1 * c - v2 * s) * scale;
        buf[base + 32 + i] = (v1 * s + v2 * c) * scale;
    }
}

// ---------------------------------------------------------------------------
__global__ void scores_gate(const float* __restrict__ x,
                            const float* __restrict__ w_imp,
                            const float* __restrict__ w_gate,
                            float* __restrict__ scores,
                            float* __restrict__ gate_raw) {
    int wid = (blockIdx.x * blockDim.x + threadIdx.x) >> 6;
    int lane = threadIdx.x & 63;
    if (wid >= BATCH * T_SEQ) return;
    int b = wid >> 10;
    const float* xr = x + (size_t)wid * CDIM;
    float s0 = 0, g0 = 0, g1 = 0, g2 = 0;
    for (int c = lane; c < CDIM; c += 64) {
        float xv = xr[c];
        s0 += xv * w_imp[c];
        g0 += xv * w_gate[c * 3 + 0];
        g1 += xv * w_gate[c * 3 + 1];
        g2 += xv * w_gate[c * 3 + 2];
    }
    for (int off = 32; off; off >>= 1) {
        s0 += __shfl_xor(s0, off, 64);
        g0 += __shfl_xor(g0, off, 64);
        g1 += __shfl_xor(g1, off, 64);
        g2 += __shfl_xor(g2, off, 64);
    }
    if (lane == 0) {
        scores[wid] = s0;
        atomicAdd(&gate_raw[b * 3 + 0], g0);
        atomicAdd(&gate_raw[b * 3 + 1], g1);
        atomicAdd(&gate_raw[b * 3 + 2], g2);
    }
}

__global__ void gate_final(const float* __restrict__ gate_raw, float* __restrict__ gate) {
    int b = threadIdx.x;
    if (b >= BATCH) return;
    float v0 = gate_raw[b * 3 + 0] / (float)T_SEQ;
    float v1 = gate_raw[b * 3 + 1] / (float)T_SEQ;
    float v2 = gate_raw[b * 3 + 2] / (float)T_SEQ;
    float m = fmaxf(v0, fmaxf(v1, v2));
    float e0 = expf(v0 - m), e1 = expf(v1 - m), e2 = expf(v2 - m);
    float s = e0 + e1 + e2;
    gate[b * 3 + 0] = e0 / s;
    gate[b * 3 + 1] = e1 / s;
    gate[b * 3 + 2] = e2 / s;
}

// ---------------------------------------------------------------------------
__global__ void topk_kernel(const float* __restrict__ scores, int* __restrict__ idx) {
    int b = blockIdx.x;
    __shared__ float s[1024];
    __shared__ int ps[1024];
    int t = threadIdx.x;
    s[t] = scores[b * T_SEQ + t];
    __syncthreads();
    float mine = s[t];
    int rank = 0;
    for (int j = 0; j < 1024; j++) {
        float v = s[j];
        rank += (v > mine) || (v == mine && j < t);
    }
    int selv = (rank < KEEP) ? 1 : 0;
    ps[t] = selv;
    __syncthreads();
    for (int off = 1; off < 1024; off <<= 1) {
        int add = (t >= off) ? ps[t - off] : 0;
        __syncthreads();
        ps[t] += add;
        __syncthreads();
    }
    if (selv) idx[b * KEEP + ps[t] - 1] = t;
}

__global__ void gather_sel(const float* __restrict__ x, const int* __restrict__ idx,
                           float* __restrict__ sel) {
    for (size_t i = (size_t)blockIdx.x * blockDim.x + threadIdx.x;
         i < (size_t)BATCH * KEEP * CDIM; i += (size_t)gridDim.x * blockDim.x) {
        int c = (int)(i & (CDIM - 1));
        int r = (int)((i >> 10) & (KEEP - 1));
        int b = (int)(i >> 18);
        sel[i] = x[((size_t)b * T_SEQ + idx[b * KEEP + r]) * CDIM + c];
    }
}

// ---------------------------------------------------------------------------
// Fused 3-branch flash attention v4 (measured-best: 399 us, occ 31%), reading
// fused/strided buffers: qp (QPW), kvp (KVW), xp (XPW, kro at +96),
// skv (SKW), wkv (WKW).
// Grid: (T/64, NHEAD, BATCH), 512 threads. LDS = 78.3 KB -> 2 blocks/CU.
// ---------------------------------------------------------------------------
__global__ __launch_bounds__(512, 4) void flash_fused(
    const float* __restrict__ qp, const float* __restrict__ kvp,
    const float* __restrict__ xp, const float* __restrict__ skv,
    const float* __restrict__ wkv, const float* __restrict__ gate,
    float* __restrict__ out) {
    __shared__ float Qs[BQ * SK];    // 64 x 96 (stride 100)
    __shared__ float Ks[BKT * SK];   // 64 x 96 (stride 100)
    __shared__ float Vs[BKT * SPV];  // 64 x 32 (stride 36)
    __shared__ float Pt[BKT * SPT];  // [k][q] (stride 66)
    __shared__ float mrow[BQ], lrow[BQ], arow[BQ], mtil[BQ];

    int b = blockIdx.z, h = blockIdx.y;
    int qt = blockIdx.x;
    if (b == 1) qt = (gridDim.x - 1) - qt;   // balance causal cost across z-pairs
    int q0 = qt * BQ;
    int t = threadIdx.x;
    int tq = t >> 4, tk = t & 15;   // S mapping: q=2*tq+i, k=16*j+tk
    int qg = t >> 4, dg = t & 15;   // PV mapping: q=2*qg+i, d=2*dg+j

    // stage Q tile (64 rows x 24 float4)
    for (int i = t; i < BQ * 24; i += 512) {
        int row = i / 24, d4 = i % 24;
        size_t rq = (size_t)b * T_SEQ + q0 + row;
        float4 v;
        if (d4 < 8) v = *(const float4*)&qp[rq * QPW + h * 32 + d4 * 4];
        else        v = *(const float4*)&qp[rq * QPW + 512 + h * 64 + (d4 - 8) * 4];
        *(float4*)&Qs[row * SK + d4 * 4] = v;
    }

    float comb[2][2] = {};
    for (int phase = 0; phase < 3; phase++) {
        bool causal = (phase != 1);
        int ntiles = causal ? (qt + 1) : (KEEP / BKT);
        float o00 = 0.f, o01 = 0.f, o10 = 0.f, o11 = 0.f;
        __syncthreads();   // previous phase readers of lrow done
        if (t < BQ) { mrow[t] = -1e30f; lrow[t] = 0.f; }

        for (int kt = 0; kt < ntiles; kt++) {
            int j0 = kt * BKT;
            __syncthreads();  // previous tile readers of Ks/Vs/Pt done

            // stage K tile (64 rows x 24 float4)
            for (int i = t; i < BKT * 24; i += 512) {
                int row = i / 24, d4 = i % 24;
                int j = j0 + row;
                float4 v;
                if (phase == 0) {
                    size_t rk = (size_t)b * T_SEQ + j;
                    if (d4 < 8) v = *(const float4*)&kvp[rk * KVW + h * 32 + d4 * 4];
                    else        v = *(const float4*)&xp[rk * XPW + 96 + (d4 - 8) * 4];
                } else if (phase == 1) {
                    v = *(const float4*)&skv[((size_t)b * KEEP + j) * SKW + h * 96 + d4 * 4];
                } else {
                    v = *(const float4*)&wkv[((size_t)b * T_SEQ + j) * WKW + h * 96 + d4 * 4];
                }
                *(float4*)&Ks[row * SK + d4 * 4] = v;
            }
            // stage V tile (64 rows x 8 float4)
            for (int i = t; i < BKT * 8; i += 512) {
                int row = i >> 3, d4 = i & 7;
                int j = j0 + row;
                float4 v;
                if (phase == 0)      v = *(const float4*)&kvp[((size_t)b * T_SEQ + j) * KVW + 512 + h * 32 + d4 * 4];
                else if (phase == 1) v = *(const float4*)&skv[((size_t)b * KEEP  + j) * SKW + 1536 + h * 32 + d4 * 4];
                else                 v = *(const float4*)&wkv[((size_t)b * T_SEQ + j) * WKW + 1536 + h * 32 + d4 * 4];
                *(float4*)&Vs[row * SPV + d4 * 4] = v;
            }
            __syncthreads();

            // S = Q.K^T  (2q x 4k per thread)
            float s[2][4] = {};
#pragma unroll 6
            for (int d = 0; d < HEAD_D; d += 4) {
                float4 qa = *(float4*)&Qs[(2 * tq)     * SK + d];
                float4 qb = *(float4*)&Qs[(2 * tq + 1) * SK + d];
#pragma unroll
                for (int j = 0; j < 4; j++) {
                    float4 kv = *(float4*)&Ks[(16 * j + tk) * SK + d];
                    s[0][j] += qa.x * kv.x + qa.y * kv.y + qa.z * kv.z + qa.w * kv.w;
                    s[1][j] += qb.x * kv.x + qb.y * kv.y + qb.z * kv.z + qb.w * kv.w;
                }
            }
#pragma unroll
            for (int i = 0; i < 2; i++)
#pragma unroll
                for (int j = 0; j < 4; j++) {
                    int qq = q0 + 2 * tq + i;
                    int kk = j0 + 16 * j + tk;
                    float sv = s[i][j] * SCALE_ATTN;
                    if (causal && kk > qq) sv = -1e30f;
                    Pt[(16 * j + tk) * SPT + (2 * tq + i)] = sv;
                }
            __syncthreads();

            // tile row-max: q = t>>3, 8 lanes per row
            {
                int q = t >> 3, sub = t & 7;
                float mt = -1e30f;
#pragma unroll
                for (int i2 = 0; i2 < 8; i2++)
                    mt = fmaxf(mt, Pt[(sub * 8 + i2) * SPT + q]);
                mt = fmaxf(mt, __shfl_xor(mt, 1, 64));
                mt = fmaxf(mt, __shfl_xor(mt, 2, 64));
                mt = fmaxf(mt, __shfl_xor(mt, 4, 64));
                if (sub == 0) mtil[q] = mt;
            }
            __syncthreads();
            if (t < BQ) {
                float mnew = fmaxf(mrow[t], mtil[t]);
                arow[t] = __expf(mrow[t] - mnew);
                mrow[t] = mnew;
            }
            __syncthreads();
            // exponentiate + row sums
            {
                int q = t >> 3, sub = t & 7;
                float mnew = mrow[q];
                float psum = 0.f;
#pragma unroll
                for (int i2 = 0; i2 < 8; i2++) {
                    int kk = sub * 8 + i2;
                    float p = __expf(Pt[kk * SPT + q] - mnew);
                    Pt[kk * SPT + q] = p;
                    psum += p;
                }
                psum += __shfl_xor(psum, 1, 64);
                psum += __shfl_xor(psum, 2, 64);
                psum += __shfl_xor(psum, 4, 64);
                if (sub == 0) lrow[q] = lrow[q] * arow[q] + psum;
            }
            __syncthreads();

            // O accumulate (2q x 2d per thread)
            {
                float a0 = arow[2 * qg], a1 = arow[2 * qg + 1];
                o00 *= a0; o01 *= a0; o10 *= a1; o11 *= a1;
#pragma unroll 8
                for (int kk = 0; kk < BKT; kk++) {
                    float2 pv = *(float2*)&Pt[kk * SPT + 2 * qg];
                    float2 vv = *(float2*)&Vs[kk * SPV + 2 * dg];
                    o00 += pv.x * vv.x; o01 += pv.x * vv.y;
                    o10 += pv.y * vv.x; o11 += pv.y * vv.y;
                }
            }
        }  // key tiles

        // gate combine
        {
            float g = gate[b * 3 + phase];
            float i0 = g / lrow[2 * qg], i1 = g / lrow[2 * qg + 1];
            comb[0][0] += o00 * i0; comb[0][1] += o01 * i0;
            comb[1][0] += o10 * i1; comb[1][1] += o11 * i1;
        }
    }  // phases

    size_t r0 = ((size_t)b * T_SEQ + q0 + 2 * qg) * 512 + h * 32 + 2 * dg;
    out[r0]           = comb[0][0];
    out[r0 + 1]       = comb[0][1];
    out[r0 + 512]     = comb[1][0];
    out[r0 + 512 + 1] = comb[1][1];
}

// ---------------------------------------------------------------------------
extern "C" void kernel_launch(void* const* d_in, const int* in_sizes, int n_in,
                              void* d_out, int out_size, void* d_ws, size_t ws_size,
                              hipStream_t stream) {
    const float* x        = (const float*)d_in[0];
    const float* w_cq     = (const float*)d_in[1];
    const float* g_qnorm  = (const float*)d_in[2];
    const float* w_dqn    = (const float*)d_in[3];
    const float* w_dqr    = (const float*)d_in[4];
    const float* w_ckv    = (const float*)d_in[5];
    const float* g_kvnorm = (const float*)d_in[6];
    const float* w_dkn    = (const float*)d_in[7];
    const float* w_dv     = (const float*)d_in[8];
    const float* w_krope  = (const float*)d_in[9];
    const float* w_imp    = (const float*)d_in[10];
    const float* w_selk   = (const float*)d_in[11];
    const float* w_selv   = (const float*)d_in[12];
    const float* w_wink   = (const float*)d_in[13];
    const float* w_winv   = (const float*)d_in[14];
    const float* w_gate   = (const float*)d_in[15];
    const float* w_proj   = (const float*)d_in[16];
    float* out = (float*)d_out;

    const int BT = BATCH * T_SEQ;  // 2048
    const int BS = BATCH * KEEP;   // 512

    float* ws = (float*)d_ws;
    size_t o = 0;
    float* xp     = ws + o; o += (size_t)BT * XPW;
    float* qp     = ws + o; o += (size_t)BT * QPW;
    float* kvp    = ws + o; o += (size_t)BT * KVW;
    float* wkv    = ws + o; o += (size_t)BT * WKW;
    float* skv    = ws + o; o += (size_t)BS * SKW;
    float* selb   = ws + o; o += (size_t)BS * CDIM;
    float* attn   = ws + o; o += (size_t)BT * 512;
    float* Bsm    = ws + o; o += (size_t)1024 * XPW;
    float* Bq     = ws + o; o += (size_t)96 * QPW;
    float* Bkv    = ws + o; o += (size_t)32 * KVW;
    float* Bw     = ws + o; o += (size_t)1024 * WKW;
    float* Bsel   = ws + o; o += (size_t)1024 * SKW;
    float* scores = ws + o; o += 2048;
    float* gateraw= ws + o; o += 8;
    float* gatef  = ws + o; o += 8;
    int*   idx    = (int*)(ws + o); o += 512;

    hipMemsetAsync(gateraw, 0, 8 * sizeof(float), stream);

    auto gemm = [&](const float* A, const float* Bm, float* C, int M, int N, int K,
                    int lda, int ldb, int ldc) {
        dim3 grid((N + 127) / 128, (M + 127) / 128);
        gemm128<<<grid, 256, 0, stream>>>(A, Bm, C, M, N, K, lda, ldb, ldc);
    };

    // weight packs (all independent)
    pack3<<<1024, 256, 0, stream>>>(Bsm, w_cq, 96, w_krope, 64, w_ckv, 32, 1024);
    pack3<<<96,   256, 0, stream>>>(Bq, w_dqn, 512, w_dqr, 1024, w_dqn, 0, 96);
    pack3<<<32,   256, 0, stream>>>(Bkv, w_dkn, 512, w_dv, 512, w_dkn, 0, 32);
    pack3<<<1024, 256, 0, stream>>>(Bw, w_wink, 1536, w_winv, 512, w_wink, 0, 1024);
    pack3<<<1024, 256, 0, stream>>>(Bsel, w_selk, 1536, w_selv, 512, w_selk, 0, 1024);

    // fused projections off x: xp = x @ [w_cq | w_krope | w_ckv]
    gemm(x, Bsm, xp, BT, XPW, CDIM, CDIM, XPW, XPW);
    rms_rows<<<BT, 64, 0, stream>>>(xp, g_qnorm, 96, XPW);          // nq  = xp[:,0:96]
    rms_rows<<<BT, 64, 0, stream>>>(xp + 160, g_kvnorm, 32, XPW);   // ckv = xp[:,160:192]
    rope_inplace<<<256, 256, 0, stream>>>(xp, BT, XPW, 1, 0, 96, T_SEQ, 1.0f / NHEAD); // kro

    // q projections: qp = nq @ [w_dqn | w_dqr]
    gemm(xp, Bq, qp, BT, QPW, 96, XPW, QPW, QPW);
    rope_inplace<<<2048, 256, 0, stream>>>(qp, BT, QPW, 16, 64, 512, T_SEQ, 1.0f);

    // kv projections: kvp = ckv @ [w_dkn | w_dv]
    gemm(xp + 160, Bkv, kvp, BT, KVW, 32, XPW, KVW, KVW);

    // window k/v: wkv = x @ [w_wink | w_winv]
    gemm(x, Bw, wkv, BT, WKW, CDIM, CDIM, WKW, WKW);
    rope_inplace<<<2048, 256, 0, stream>>>(wkv, BT, WKW, 16, 96, 32, T_SEQ, 1.0f);

    // scores + gate
    scores_gate<<<(BT * 64 + 255) / 256, 256, 0, stream>>>(x, w_imp, w_gate, scores, gateraw);
    gate_final<<<1, 64, 0, stream>>>(gateraw, gatef);

    // top-k select + selected k/v: skv = sel @ [w_selk | w_selv]
    topk_kernel<<<BATCH, 1024, 0, stream>>>(scores, idx);
    gather_sel<<<2048, 256, 0, stream>>>(x, idx, selb);
    gemm(selb, Bsel, skv, BS, SKW, CDIM, CDIM, SKW, SKW);
    rope_inplace<<<512, 256, 0, stream>>>(skv, BS, SKW, 16, 96, 32, KEEP, 1.0f);

    // fused attention
    dim3 fgrid(T_SEQ / BQ, NHEAD, BATCH);
    flash_fused<<<fgrid, 512, 0, stream>>>(qp, kvp, xp, skv, wkv, gatef, attn);

    // output projection (no pack: single B)
    gemm(attn, w_proj, out, BT, CDIM, 512, 512, CDIM, CDIM);
}

// Round 7
// 1032.970 us; speedup vs baseline: 2.6188x; 1.2312x over previous
//
#include <hip/hip_runtime.h>
#include <math.h>

#define T_SEQ   1024
#define BATCH   2
#define CDIM    1024
#define NHEAD   16
#define VHEAD   32
#define KEEP    256
#define HEAD_D  96   // NOPE + ROPE
#define SCALE_ATTN 0.1020620726159658f  // 1/sqrt(96)

// flash tile params
#define BQ   64
#define BKT  64
#define SK   100    // Q/K LDS row stride: 100%32=4 -> <=2-way on b128 (free)
#define SPT  66     // Pt row stride [k][q]
#define SPV  36     // V LDS row stride

// GEMM tile params: 128x128 block, 8x8 micro, single-buffered (spill-safe)
#define GBK 16
#define SA  132     // padded row stride: 132%32=4 -> <=2-way (free)

// XW layout: x @ [cq | ckv | krope | wink | winv | imp | gate]
#define XWW    2244
#define C_CQ   0      // 96
#define C_CKV  96     // 32
#define C_KRO  128    // 64
#define C_WINK 192    // 1536 (16 heads x 96)
#define C_WINV 1728   // 512  (16 heads x 32)
#define C_IMP  2240   // 1
#define C_GATE 2241   // 3

// QKV layout: [nq|ckv] @ blockdiag -> [qn | qr | kn | v1]
#define QKVW   2560
#define C_QN   0      // 512
#define C_QR   512    // 1024
#define C_KN   1536   // 512
#define C_V1   2048   // 512

#define SKW  2048   // skv: [0:1536) ks | [1536:2048) vs

// ---------------------------------------------------------------------------
// fp32 GEMM (measured-good v4): C[M,N] = A[M,K] @ B[K,N], strides lda/ldb/ldc.
// 128x128 block, 256 threads, 8x8 micro-tile, single LDS buffer, ~95 VGPR.
// Requires K%16==0; M,N guarded.
// ---------------------------------------------------------------------------
__global__ __launch_bounds__(256) void gemm128(const float* __restrict__ A,
                                               const float* __restrict__ B,
                                               float* __restrict__ C,
                                               int M, int N, int K,
                                               int lda, int ldb, int ldc) {
    __shared__ float As[GBK][SA];   // [k][m] transposed A tile
    __shared__ float Bs[GBK][SA];   // [k][n]
    int t = threadIdx.x;
    int tx = t & 15, ty = t >> 4;
    int row0 = blockIdx.y * 128, col0 = blockIdx.x * 128;
    float acc[8][8] = {};

    for (int k0 = 0; k0 < K; k0 += GBK) {
#pragma unroll
        for (int r = 0; r < 2; r++) {
            int idx = t + 256 * r;            // 0..511
            int row = idx >> 2, k4 = idx & 3;
            int gr = row0 + row;
            float4 v = make_float4(0.f, 0.f, 0.f, 0.f);
            if (gr < M) v = *(const float4*)&A[(size_t)gr * lda + k0 + k4 * 4];
            As[k4 * 4 + 0][row] = v.x;
            As[k4 * 4 + 1][row] = v.y;
            As[k4 * 4 + 2][row] = v.z;
            As[k4 * 4 + 3][row] = v.w;
        }
#pragma unroll
        for (int r = 0; r < 2; r++) {
            int idx = t + 256 * r;
            int kk = idx >> 5, n4 = idx & 31;
            int gc = col0 + n4 * 4;
            float4 v = make_float4(0.f, 0.f, 0.f, 0.f);
            if (gc + 3 < N) {
                v = *(const float4*)&B[(size_t)(k0 + kk) * ldb + gc];
            } else if (gc < N) {
                const float* bp = &B[(size_t)(k0 + kk) * ldb];
                float tmp[4] = {0.f, 0.f, 0.f, 0.f};
                for (int j = 0; j < 4 && gc + j < N; j++) tmp[j] = bp[gc + j];
                v = make_float4(tmp[0], tmp[1], tmp[2], tmp[3]);
            }
            *(float4*)&Bs[kk][n4 * 4] = v;
        }
        __syncthreads();
#pragma unroll
        for (int kk = 0; kk < GBK; kk++) {
            float4 a0 = *(float4*)&As[kk][ty * 4];
            float4 a1 = *(float4*)&As[kk][64 + ty * 4];
            float4 b0 = *(float4*)&Bs[kk][tx * 4];
            float4 b1 = *(float4*)&Bs[kk][64 + tx * 4];
            float av[8] = {a0.x, a0.y, a0.z, a0.w, a1.x, a1.y, a1.z, a1.w};
            float bv[8] = {b0.x, b0.y, b0.z, b0.w, b1.x, b1.y, b1.z, b1.w};
#pragma unroll
            for (int i = 0; i < 8; i++)
#pragma unroll
                for (int j = 0; j < 8; j++) acc[i][j] += av[i] * bv[j];
        }
        __syncthreads();
    }

#pragma unroll
    for (int i = 0; i < 8; i++) {
        int gr = row0 + ((i < 4) ? (ty * 4 + i) : (64 + ty * 4 + (i - 4)));
        if (gr >= M) continue;
        int gc0 = col0 + tx * 4;
        if (gc0 + 3 < N)
            *(float4*)&C[(size_t)gr * ldc + gc0] =
                make_float4(acc[i][0], acc[i][1], acc[i][2], acc[i][3]);
        int gc1 = col0 + 64 + tx * 4;
        if (gc1 + 3 < N)
            *(float4*)&C[(size_t)gr * ldc + gc1] =
                make_float4(acc[i][4], acc[i][5], acc[i][6], acc[i][7]);
    }
}

// ---------------------------------------------------------------------------
// pack the 7-way x-side weight concat: [cq 96 | ckv 32 | krope 64 | wink 1536
//  | winv 512 | imp 1 | gate 3], rows = 1024
__global__ void pack_xw(float* __restrict__ dst,
                        const float* __restrict__ cq, const float* __restrict__ ckv,
                        const float* __restrict__ kro, const float* __restrict__ wink,
                        const float* __restrict__ winv, const float* __restrict__ imp,
                        const float* __restrict__ gate) {
    int r = blockIdx.x;
    for (int c = threadIdx.x; c < XWW; c += blockDim.x) {
        float v;
        if      (c < C_CKV)  v = cq  [(size_t)r * 96   + c];
        else if (c < C_KRO)  v = ckv [(size_t)r * 32   + (c - C_CKV)];
        else if (c < C_WINK) v = kro [(size_t)r * 64   + (c - C_KRO)];
        else if (c < C_WINV) v = wink[(size_t)r * 1536 + (c - C_WINK)];
        else if (c < C_IMP)  v = winv[(size_t)r * 512  + (c - C_WINV)];
        else if (c < C_GATE) v = imp [(size_t)r * 1    + (c - C_IMP)];
        else                 v = gate[(size_t)r * 3    + (c - C_GATE)];
        dst[(size_t)r * XWW + c] = v;
    }
}

// block-diagonal pack: rows 0..95 = [dqn 512 | dqr 1024 | 0 | 0],
// rows 96..127 = [0 | 0 | dkn 512 | dv 512]; dst 128 x 2560
__global__ void pack_qkv(float* __restrict__ dst,
                         const float* __restrict__ dqn, const float* __restrict__ dqr,
                         const float* __restrict__ dkn, const float* __restrict__ dv) {
    int r = blockIdx.x;
    for (int c = threadIdx.x; c < QKVW; c += blockDim.x) {
        float v = 0.f;
        if (r < 96) {
            if (c < C_QR)      v = dqn[(size_t)r * 512 + c];
            else if (c < C_KN) v = dqr[(size_t)r * 1024 + (c - C_QR)];
        } else {
            if (c >= C_KN && c < C_V1) v = dkn[(size_t)(r - 96) * 512 + (c - C_KN)];
            else if (c >= C_V1)        v = dv [(size_t)(r - 96) * 512 + (c - C_V1)];
        }
        dst[(size_t)r * QKVW + c] = v;
    }
}

// pack2: dst[r] = [s0[r] | s1[r]]
__global__ void pack2(float* __restrict__ dst,
                      const float* __restrict__ s0, int w0,
                      const float* __restrict__ s1, int w1) {
    int W = w0 + w1;
    int r = blockIdx.x;
    for (int c = threadIdx.x; c < W; c += blockDim.x) {
        float v = (c < w0) ? s0[(size_t)r * w0 + c] : s1[(size_t)r * w1 + (c - w0)];
        dst[(size_t)r * W + c] = v;
    }
}

// ---------------------------------------------------------------------------
__global__ void rms_rows(float* __restrict__ buf, const float* __restrict__ g,
                         int D, int stride) {
    int row = blockIdx.x;
    int lane = threadIdx.x;  // blockDim = 64
    float* rp = buf + (size_t)row * stride;
    float ss = 0.f;
    for (int d = lane; d < D; d += 64) {
        float v = rp[d];
        ss += v * v;
    }
    for (int off = 32; off; off >>= 1) ss += __shfl_xor(ss, off, 64);
    float r = rsqrtf(ss / (float)D + 1e-6f);
    for (int d = lane; d < D; d += 64) rp[d] *= r * g[d];
}

// ---------------------------------------------------------------------------
__global__ void rope_inplace(float* __restrict__ buf, int nrows, int rstride,
                             int nheads, int hstride, int roff, int posmod,
                             float scale) {
    int total = nrows * nheads * 32;
    for (int it = blockIdx.x * blockDim.x + threadIdx.x; it < total;
         it += gridDim.x * blockDim.x) {
        int i = it & 31;
        int hr = it >> 5;
        int h = hr % nheads;
        int row = hr / nheads;
        int pos = row % posmod;
        float expo = (float)i * (1.0f / 32.0f);
        float f = 1.0f / powf(10000.0f, expo);
        float a = (float)pos * f;
        float s, c;
        sincosf(a, &s, &c);
        size_t base = (size_t)row * rstride + (size_t)h * hstride + roff;
        float v1 = buf[base + i], v2 = buf[base + 32 + i];
        buf[base + i]      = (v1 * c - v2 * s) * scale;
        buf[base + 32 + i] = (v1 * s + v2 * c) * scale;
    }
}

// ---------------------------------------------------------------------------
// gate = softmax over c of mean_t XW[b,t,C_GATE+c]; grid = BATCH, 256 threads
__global__ void gate_from_cols(const float* __restrict__ xw, float* __restrict__ gate) {
    int b = blockIdx.x;
    int t = threadIdx.x;
    __shared__ float red[3][4];
    float g0 = 0.f, g1 = 0.f, g2 = 0.f;
    for (int r = t; r < T_SEQ; r += 256) {
        const float* p = &xw[((size_t)b * T_SEQ + r) * XWW + C_GATE];
        g0 += p[0]; g1 += p[1]; g2 += p[2];
    }
    for (int off = 32; off; off >>= 1) {
        g0 += __shfl_xor(g0, off, 64);
        g1 += __shfl_xor(g1, off, 64);
        g2 += __shfl_xor(g2, off, 64);
    }
    int w = t >> 6;
    if ((t & 63) == 0) { red[0][w] = g0; red[1][w] = g1; red[2][w] = g2; }
    __syncthreads();
    if (t == 0) {
        float v0 = (red[0][0] + red[0][1] + red[0][2] + red[0][3]) / (float)T_SEQ;
        float v1 = (red[1][0] + red[1][1] + red[1][2] + red[1][3]) / (float)T_SEQ;
        float v2 = (red[2][0] + red[2][1] + red[2][2] + red[2][3]) / (float)T_SEQ;
        float m = fmaxf(v0, fmaxf(v1, v2));
        float e0 = expf(v0 - m), e1 = expf(v1 - m), e2 = expf(v2 - m);
        float s = e0 + e1 + e2;
        gate[b * 3 + 0] = e0 / s;
        gate[b * 3 + 1] = e1 / s;
        gate[b * 3 + 2] = e2 / s;
    }
}

// ---------------------------------------------------------------------------
// topk over strided score column
__global__ void topk_kernel(const float* __restrict__ base, int stride, int col,
                            int* __restrict__ idx) {
    int b = blockIdx.x;
    __shared__ float s[1024];
    __shared__ int ps[1024];
    int t = threadIdx.x;
    s[t] = base[((size_t)b * T_SEQ + t) * stride + col];
    __syncthreads();
    float mine = s[t];
    int rank = 0;
    for (int j = 0; j < 1024; j++) {
        float v = s[j];
        rank += (v > mine) || (v == mine && j < t);
    }
    int selv = (rank < KEEP) ? 1 : 0;
    ps[t] = selv;
    __syncthreads();
    for (int off = 1; off < 1024; off <<= 1) {
        int add = (t >= off) ? ps[t - off] : 0;
        __syncthreads();
        ps[t] += add;
        __syncthreads();
    }
    if (selv) idx[b * KEEP + ps[t] - 1] = t;
}

__global__ void gather_sel(const float* __restrict__ x, const int* __restrict__ idx,
                           float* __restrict__ sel) {
    for (size_t i = (size_t)blockIdx.x * blockDim.x + threadIdx.x;
         i < (size_t)BATCH * KEEP * CDIM; i += (size_t)gridDim.x * blockDim.x) {
        int c = (int)(i & (CDIM - 1));
        int r = (int)((i >> 10) & (KEEP - 1));
        int b = (int)(i >> 18);
        sel[i] = x[((size_t)b * T_SEQ + idx[b * KEEP + r]) * CDIM + c];
    }
}

// ---------------------------------------------------------------------------
// Fused 3-branch flash attention (measured-best: 397 us), reading QKV / XW /
// skv fused buffers. Grid: (T/64, NHEAD, BATCH), 512 threads. LDS 78.3 KB.
// ---------------------------------------------------------------------------
__global__ __launch_bounds__(512, 4) void flash_fused(
    const float* __restrict__ qkv, const float* __restrict__ xw,
    const float* __restrict__ skv, const float* __restrict__ gate,
    float* __restrict__ out) {
    __shared__ float Qs[BQ * SK];
    __shared__ float Ks[BKT * SK];
    __shared__ float Vs[BKT * SPV];
    __shared__ float Pt[BKT * SPT];
    __shared__ float mrow[BQ], lrow[BQ], arow[BQ], mtil[BQ];

    int b = blockIdx.z, h = blockIdx.y;
    int qt = blockIdx.x;
    if (b == 1) qt = (gridDim.x - 1) - qt;   // balance causal cost across z-pairs
    int q0 = qt * BQ;
    int t = threadIdx.x;
    int tq = t >> 4, tk = t & 15;
    int qg = t >> 4, dg = t & 15;

    // stage Q tile (64 rows x 24 float4)
    for (int i = t; i < BQ * 24; i += 512) {
        int row = i / 24, d4 = i % 24;
        size_t rq = (size_t)b * T_SEQ + q0 + row;
        float4 v;
        if (d4 < 8) v = *(const float4*)&qkv[rq * QKVW + C_QN + h * 32 + d4 * 4];
        else        v = *(const float4*)&qkv[rq * QKVW + C_QR + h * 64 + (d4 - 8) * 4];
        *(float4*)&Qs[row * SK + d4 * 4] = v;
    }

    float comb[2][2] = {};
    for (int phase = 0; phase < 3; phase++) {
        bool causal = (phase != 1);
        int ntiles = causal ? (qt + 1) : (KEEP / BKT);
        float o00 = 0.f, o01 = 0.f, o10 = 0.f, o11 = 0.f;
        __syncthreads();
        if (t < BQ) { mrow[t] = -1e30f; lrow[t] = 0.f; }

        for (int kt = 0; kt < ntiles; kt++) {
            int j0 = kt * BKT;
            __syncthreads();

            // stage K tile
            for (int i = t; i < BKT * 24; i += 512) {
                int row = i / 24, d4 = i % 24;
                int j = j0 + row;
                float4 v;
                if (phase == 0) {
                    size_t rk = (size_t)b * T_SEQ + j;
                    if (d4 < 8) v = *(const float4*)&qkv[rk * QKVW + C_KN + h * 32 + d4 * 4];
                    else        v = *(const float4*)&xw[rk * XWW + C_KRO + (d4 - 8) * 4];
                } else if (phase == 1) {
                    v = *(const float4*)&skv[((size_t)b * KEEP + j) * SKW + h * 96 + d4 * 4];
                } else {
                    v = *(const float4*)&xw[((size_t)b * T_SEQ + j) * XWW + C_WINK + h * 96 + d4 * 4];
                }
                *(float4*)&Ks[row * SK + d4 * 4] = v;
            }
            // stage V tile
            for (int i = t; i < BKT * 8; i += 512) {
                int row = i >> 3, d4 = i & 7;
                int j = j0 + row;
                float4 v;
                if (phase == 0)      v = *(const float4*)&qkv[((size_t)b * T_SEQ + j) * QKVW + C_V1 + h * 32 + d4 * 4];
                else if (phase == 1) v = *(const float4*)&skv[((size_t)b * KEEP  + j) * SKW + 1536 + h * 32 + d4 * 4];
                else                 v = *(const float4*)&xw[((size_t)b * T_SEQ + j) * XWW + C_WINV + h * 32 + d4 * 4];
                *(float4*)&Vs[row * SPV + d4 * 4] = v;
            }
            __syncthreads();

            // S = Q.K^T (2q x 4k per thread)
            float s[2][4] = {};
#pragma unroll 6
            for (int d = 0; d < HEAD_D; d += 4) {
                float4 qa = *(float4*)&Qs[(2 * tq)     * SK + d];
                float4 qb = *(float4*)&Qs[(2 * tq + 1) * SK + d];
#pragma unroll
                for (int j = 0; j < 4; j++) {
                    float4 kv = *(float4*)&Ks[(16 * j + tk) * SK + d];
                    s[0][j] += qa.x * kv.x + qa.y * kv.y + qa.z * kv.z + qa.w * kv.w;
                    s[1][j] += qb.x * kv.x + qb.y * kv.y + qb.z * kv.z + qb.w * kv.w;
                }
            }
#pragma unroll
            for (int i = 0; i < 2; i++)
#pragma unroll
                for (int j = 0; j < 4; j++) {
                    int qq = q0 + 2 * tq + i;
                    int kk = j0 + 16 * j + tk;
                    float sv = s[i][j] * SCALE_ATTN;
                    if (causal && kk > qq) sv = -1e30f;
                    Pt[(16 * j + tk) * SPT + (2 * tq + i)] = sv;
                }
            __syncthreads();

            // tile row-max
            {
                int q = t >> 3, sub = t & 7;
                float mt = -1e30f;
#pragma unroll
                for (int i2 = 0; i2 < 8; i2++)
                    mt = fmaxf(mt, Pt[(sub * 8 + i2) * SPT + q]);
                mt = fmaxf(mt, __shfl_xor(mt, 1, 64));
                mt = fmaxf(mt, __shfl_xor(mt, 2, 64));
                mt = fmaxf(mt, __shfl_xor(mt, 4, 64));
                if (sub == 0) mtil[q] = mt;
            }
            __syncthreads();
            if (t < BQ) {
                float mnew = fmaxf(mrow[t], mtil[t]);
                arow[t] = __expf(mrow[t] - mnew);
                mrow[t] = mnew;
            }
            __syncthreads();
            // exponentiate + row sums
            {
                int q = t >> 3, sub = t & 7;
                float mnew = mrow[q];
                float psum = 0.f;
#pragma unroll
                for (int i2 = 0; i2 < 8; i2++) {
                    int kk = sub * 8 + i2;
                    float p = __expf(Pt[kk * SPT + q] - mnew);
                    Pt[kk * SPT + q] = p;
                    psum += p;
                }
                psum += __shfl_xor(psum, 1, 64);
                psum += __shfl_xor(psum, 2, 64);
                psum += __shfl_xor(psum, 4, 64);
                if (sub == 0) lrow[q] = lrow[q] * arow[q] + psum;
            }
            __syncthreads();

            // O accumulate (2q x 2d per thread)
            {
                float a0 = arow[2 * qg], a1 = arow[2 * qg + 1];
                o00 *= a0; o01 *= a0; o10 *= a1; o11 *= a1;
#pragma unroll 8
                for (int kk = 0; kk < BKT; kk++) {
                    float2 pv = *(float2*)&Pt[kk * SPT + 2 * qg];
                    float2 vv = *(float2*)&Vs[kk * SPV + 2 * dg];
                    o00 += pv.x * vv.x; o01 += pv.x * vv.y;
                    o10 += pv.y * vv.x; o11 += pv.y * vv.y;
                }
            }
        }  // key tiles

        // gate combine
        {
            float g = gate[b * 3 + phase];
            float i0 = g / lrow[2 * qg], i1 = g / lrow[2 * qg + 1];
            comb[0][0] += o00 * i0; comb[0][1] += o01 * i0;
            comb[1][0] += o10 * i1; comb[1][1] += o11 * i1;
        }
    }  // phases

    size_t r0 = ((size_t)b * T_SEQ + q0 + 2 * qg) * 512 + h * 32 + 2 * dg;
    out[r0]           = comb[0][0];
    out[r0 + 1]       = comb[0][1];
    out[r0 + 512]     = comb[1][0];
    out[r0 + 512 + 1] = comb[1][1];
}

// ---------------------------------------------------------------------------
extern "C" void kernel_launch(void* const* d_in, const int* in_sizes, int n_in,
                              void* d_out, int out_size, void* d_ws, size_t ws_size,
                              hipStream_t stream) {
    const float* x        = (const float*)d_in[0];
    const float* w_cq     = (const float*)d_in[1];
    const float* g_qnorm  = (const float*)d_in[2];
    const float* w_dqn    = (const float*)d_in[3];
    const float* w_dqr    = (const float*)d_in[4];
    const float* w_ckv    = (const float*)d_in[5];
    const float* g_kvnorm = (const float*)d_in[6];
    const float* w_dkn    = (const float*)d_in[7];
    const float* w_dv     = (const float*)d_in[8];
    const float* w_krope  = (const float*)d_in[9];
    const float* w_imp    = (const float*)d_in[10];
    const float* w_selk   = (const float*)d_in[11];
    const float* w_selv   = (const float*)d_in[12];
    const float* w_wink   = (const float*)d_in[13];
    const float* w_winv   = (const float*)d_in[14];
    const float* w_gate   = (const float*)d_in[15];
    const float* w_proj   = (const float*)d_in[16];
    float* out = (float*)d_out;

    const int BT = BATCH * T_SEQ;  // 2048
    const int BS = BATCH * KEEP;   // 512

    float* ws = (float*)d_ws;
    size_t o = 0;
    float* XW     = ws + o; o += (size_t)BT * XWW;     // 18.4 MB
    float* QKV    = ws + o; o += (size_t)BT * QKVW;    // 21.0 MB
    float* skv    = ws + o; o += (size_t)BS * SKW;
    float* selb   = ws + o; o += (size_t)BS * CDIM;
    float* attn   = ws + o; o += (size_t)BT * 512;
    float* Bxw    = ws + o; o += (size_t)CDIM * XWW;   // 9.2 MB
    float* Bqkv   = ws + o; o += (size_t)128 * QKVW;
    float* Bsel   = ws + o; o += (size_t)CDIM * SKW;   // 8.4 MB
    float* gatef  = ws + o; o += 8;
    int*   idx    = (int*)(ws + o); o += 512;

    auto gemm = [&](const float* A, const float* Bm, float* C, int M, int N, int K,
                    int lda, int ldb, int ldc) {
        dim3 grid((N + 127) / 128, (M + 127) / 128);
        gemm128<<<grid, 256, 0, stream>>>(A, Bm, C, M, N, K, lda, ldb, ldc);
    };

    // weight packs (independent)
    pack_xw<<<1024, 256, 0, stream>>>(Bxw, w_cq, w_ckv, w_krope, w_wink, w_winv,
                                      w_imp, w_gate);
    pack_qkv<<<128, 256, 0, stream>>>(Bqkv, w_dqn, w_dqr, w_dkn, w_dv);
    pack2<<<1024, 256, 0, stream>>>(Bsel, w_selk, 1536, w_selv, 512);

    // GEMM1: everything off x in one wide launch (grid 18x16 = 288)
    gemm(x, Bxw, XW, BT, XWW, CDIM, CDIM, XWW, XWW);

    // norms + ropes on XW slices
    rms_rows<<<BT, 64, 0, stream>>>(XW + C_CQ, g_qnorm, 96, XWW);
    rms_rows<<<BT, 64, 0, stream>>>(XW + C_CKV, g_kvnorm, 32, XWW);
    rope_inplace<<<256, 256, 0, stream>>>(XW, BT, XWW, 1, 0, C_KRO, T_SEQ, 1.0f / NHEAD);
    rope_inplace<<<2048, 256, 0, stream>>>(XW, BT, XWW, 16, 96, C_WINK + 32, T_SEQ, 1.0f);

    // gate + topk from XW columns
    gate_from_cols<<<BATCH, 256, 0, stream>>>(XW, gatef);
    topk_kernel<<<BATCH, 1024, 0, stream>>>(XW, XWW, C_IMP, idx);
    gather_sel<<<2048, 256, 0, stream>>>(x, idx, selb);

    // GEMM2: QKV = [nq|ckv] @ blockdiag (grid 20x16 = 320, K=128)
    gemm(XW, Bqkv, QKV, BT, QKVW, 128, XWW, QKVW, QKVW);
    rope_inplace<<<2048, 256, 0, stream>>>(QKV, BT, QKVW, 16, 64, C_QR, T_SEQ, 1.0f);

    // GEMM3: skv = sel @ [w_selk | w_selv]
    gemm(selb, Bsel, skv, BS, SKW, CDIM, CDIM, SKW, SKW);
    rope_inplace<<<512, 256, 0, stream>>>(skv, BS, SKW, 16, 96, 32, KEEP, 1.0f);

    // fused attention
    dim3 fgrid(T_SEQ / BQ, NHEAD, BATCH);
    flash_fused<<<fgrid, 512, 0, stream>>>(QKV, XW, skv, gatef, attn);

    // output projection
    gemm(attn, w_proj, out, BT, CDIM, 512, 512, CDIM, CDIM);
}

// Round 8
// 1001.021 us; speedup vs baseline: 2.7024x; 1.0319x over previous
//
#include <hip/hip_runtime.h>
#include <math.h>

#define T_SEQ   1024
#define BATCH   2
#define CDIM    1024
#define NHEAD   16
#define VHEAD   32
#define KEEP    256
#define HEAD_D  96   // NOPE + ROPE
#define SCALE_ATTN 0.1020620726159658f  // 1/sqrt(96)

// flash tile params
#define BQ   64
#define BKT  64
#define SK   100    // Q/K LDS row stride: 100%32=4 -> <=2-way on b128 (free)
#define SPT  66     // Pt row stride [k][q]
#define SPV  36     // V LDS row stride

// GEMM tile params: 128x128 block, 8x8 micro, single-buffered (spill-safe)
#define GBK 16
#define SA  132     // padded row stride: 132%32=4 -> <=2-way (free)

// XW layout: x @ [cq | ckv | krope | wink | winv | imp | gate]
#define XWW    2244
#define C_CQ   0      // 96
#define C_CKV  96     // 32
#define C_KRO  128    // 64
#define C_WINK 192    // 1536 (16 heads x 96)
#define C_WINV 1728   // 512  (16 heads x 32)
#define C_IMP  2240   // 1
#define C_GATE 2241   // 3

// QKV layout: [nq|ckv] @ blockdiag -> [qn | qr | kn | v1]
#define QKVW   2560
#define C_QN   0      // 512
#define C_QR   512    // 1024
#define C_KN   1536   // 512
#define C_V1   2048   // 512

#define SKW  2048   // skv: [0:1536) ks | [1536:2048) vs

// ---------------------------------------------------------------------------
// fp32 GEMM: C[M,N] = A[M,K] @ B[K,N], strides lda/ldb/ldc.
// 128x128 block, 256 threads, 8x8 micro-tile, single LDS buffer, ~95 VGPR.
// Split-K: blockIdx.z picks K-chunk [z*kchunk, min(K,(z+1)*kchunk));
// gridDim.z>1 -> partials accumulated via atomicAdd (C must be zeroed).
// Requires kchunk%16==0; M,N guarded.
// ---------------------------------------------------------------------------
__global__ __launch_bounds__(256) void gemm128(const float* __restrict__ A,
                                               const float* __restrict__ B,
                                               float* __restrict__ C,
                                               int M, int N, int K,
                                               int lda, int ldb, int ldc,
                                               int kchunk) {
    __shared__ float As[GBK][SA];   // [k][m] transposed A tile
    __shared__ float Bs[GBK][SA];   // [k][n]
    int t = threadIdx.x;
    int tx = t & 15, ty = t >> 4;
    int row0 = blockIdx.y * 128, col0 = blockIdx.x * 128;
    int kb = blockIdx.z * kchunk;
    int ke = min(K, kb + kchunk);
    float acc[8][8] = {};

    for (int k0 = kb; k0 < ke; k0 += GBK) {
#pragma unroll
        for (int r = 0; r < 2; r++) {
            int idx = t + 256 * r;            // 0..511
            int row = idx >> 2, k4 = idx & 3;
            int gr = row0 + row;
            float4 v = make_float4(0.f, 0.f, 0.f, 0.f);
            if (gr < M) v = *(const float4*)&A[(size_t)gr * lda + k0 + k4 * 4];
            As[k4 * 4 + 0][row] = v.x;
            As[k4 * 4 + 1][row] = v.y;
            As[k4 * 4 + 2][row] = v.z;
            As[k4 * 4 + 3][row] = v.w;
        }
#pragma unroll
        for (int r = 0; r < 2; r++) {
            int idx = t + 256 * r;
            int kk = idx >> 5, n4 = idx & 31;
            int gc = col0 + n4 * 4;
            float4 v = make_float4(0.f, 0.f, 0.f, 0.f);
            if (gc + 3 < N) {
                v = *(const float4*)&B[(size_t)(k0 + kk) * ldb + gc];
            } else if (gc < N) {
                const float* bp = &B[(size_t)(k0 + kk) * ldb];
                float tmp[4] = {0.f, 0.f, 0.f, 0.f};
                for (int j = 0; j < 4 && gc + j < N; j++) tmp[j] = bp[gc + j];
                v = make_float4(tmp[0], tmp[1], tmp[2], tmp[3]);
            }
            *(float4*)&Bs[kk][n4 * 4] = v;
        }
        __syncthreads();
#pragma unroll
        for (int kk = 0; kk < GBK; kk++) {
            float4 a0 = *(float4*)&As[kk][ty * 4];
            float4 a1 = *(float4*)&As[kk][64 + ty * 4];
            float4 b0 = *(float4*)&Bs[kk][tx * 4];
            float4 b1 = *(float4*)&Bs[kk][64 + tx * 4];
            float av[8] = {a0.x, a0.y, a0.z, a0.w, a1.x, a1.y, a1.z, a1.w};
            float bv[8] = {b0.x, b0.y, b0.z, b0.w, b1.x, b1.y, b1.z, b1.w};
#pragma unroll
            for (int i = 0; i < 8; i++)
#pragma unroll
                for (int j = 0; j < 8; j++) acc[i][j] += av[i] * bv[j];
        }
        __syncthreads();
    }

    bool split = (gridDim.z > 1);
#pragma unroll
    for (int i = 0; i < 8; i++) {
        int gr = row0 + ((i < 4) ? (ty * 4 + i) : (64 + ty * 4 + (i - 4)));
        if (gr >= M) continue;
#pragma unroll
        for (int half = 0; half < 2; half++) {
            int gc = col0 + half * 64 + tx * 4;
            if (gc + 3 >= N) continue;
            float* cp = &C[(size_t)gr * ldc + gc];
            if (split) {
                atomicAdd(cp + 0, acc[i][half * 4 + 0]);
                atomicAdd(cp + 1, acc[i][half * 4 + 1]);
                atomicAdd(cp + 2, acc[i][half * 4 + 2]);
                atomicAdd(cp + 3, acc[i][half * 4 + 3]);
            } else {
                *(float4*)cp = make_float4(acc[i][half * 4 + 0], acc[i][half * 4 + 1],
                                           acc[i][half * 4 + 2], acc[i][half * 4 + 3]);
            }
        }
    }
}

// ---------------------------------------------------------------------------
// pack the 7-way x-side weight concat: [cq 96 | ckv 32 | krope 64 | wink 1536
//  | winv 512 | imp 1 | gate 3], rows = 1024
__global__ void pack_xw(float* __restrict__ dst,
                        const float* __restrict__ cq, const float* __restrict__ ckv,
                        const float* __restrict__ kro, const float* __restrict__ wink,
                        const float* __restrict__ winv, const float* __restrict__ imp,
                        const float* __restrict__ gate) {
    int r = blockIdx.x;
    for (int c = threadIdx.x; c < XWW; c += blockDim.x) {
        float v;
        if      (c < C_CKV)  v = cq  [(size_t)r * 96   + c];
        else if (c < C_KRO)  v = ckv [(size_t)r * 32   + (c - C_CKV)];
        else if (c < C_WINK) v = kro [(size_t)r * 64   + (c - C_KRO)];
        else if (c < C_WINV) v = wink[(size_t)r * 1536 + (c - C_WINK)];
        else if (c < C_IMP)  v = winv[(size_t)r * 512  + (c - C_WINV)];
        else if (c < C_GATE) v = imp [(size_t)r * 1    + (c - C_IMP)];
        else                 v = gate[(size_t)r * 3    + (c - C_GATE)];
        dst[(size_t)r * XWW + c] = v;
    }
}

// block-diagonal pack: rows 0..95 = [dqn 512 | dqr 1024 | 0 | 0],
// rows 96..127 = [0 | 0 | dkn 512 | dv 512]; dst 128 x 2560
__global__ void pack_qkv(float* __restrict__ dst,
                         const float* __restrict__ dqn, const float* __restrict__ dqr,
                         const float* __restrict__ dkn, const float* __restrict__ dv) {
    int r = blockIdx.x;
    for (int c = threadIdx.x; c < QKVW; c += blockDim.x) {
        float v = 0.f;
        if (r < 96) {
            if (c < C_QR)      v = dqn[(size_t)r * 512 + c];
            else if (c < C_KN) v = dqr[(size_t)r * 1024 + (c - C_QR)];
        } else {
            if (c >= C_KN && c < C_V1) v = dkn[(size_t)(r - 96) * 512 + (c - C_KN)];
            else if (c >= C_V1)        v = dv [(size_t)(r - 96) * 512 + (c - C_V1)];
        }
        dst[(size_t)r * QKVW + c] = v;
    }
}

// pack2: dst[r] = [s0[r] | s1[r]]
__global__ void pack2(float* __restrict__ dst,
                      const float* __restrict__ s0, int w0,
                      const float* __restrict__ s1, int w1) {
    int W = w0 + w1;
    int r = blockIdx.x;
    for (int c = threadIdx.x; c < W; c += blockDim.x) {
        float v = (c < w0) ? s0[(size_t)r * w0 + c] : s1[(size_t)r * w1 + (c - w0)];
        dst[(size_t)r * W + c] = v;
    }
}

// ---------------------------------------------------------------------------
__global__ void rms_rows(float* __restrict__ buf, const float* __restrict__ g,
                         int D, int stride) {
    int row = blockIdx.x;
    int lane = threadIdx.x;  // blockDim = 64
    float* rp = buf + (size_t)row * stride;
    float ss = 0.f;
    for (int d = lane; d < D; d += 64) {
        float v = rp[d];
        ss += v * v;
    }
    for (int off = 32; off; off >>= 1) ss += __shfl_xor(ss, off, 64);
    float r = rsqrtf(ss / (float)D + 1e-6f);
    for (int d = lane; d < D; d += 64) rp[d] *= r * g[d];
}

// ---------------------------------------------------------------------------
__global__ void rope_inplace(float* __restrict__ buf, int nrows, int rstride,
                             int nheads, int hstride, int roff, int posmod,
                             float scale) {
    int total = nrows * nheads * 32;
    for (int it = blockIdx.x * blockDim.x + threadIdx.x; it < total;
         it += gridDim.x * blockDim.x) {
        int i = it & 31;
        int hr = it >> 5;
        int h = hr % nheads;
        int row = hr / nheads;
        int pos = row % posmod;
        float expo = (float)i * (1.0f / 32.0f);
        float f = 1.0f / powf(10000.0f, expo);
        float a = (float)pos * f;
        float s, c;
        sincosf(a, &s, &c);
        size_t base = (size_t)row * rstride + (size_t)h * hstride + roff;
        float v1 = buf[base + i], v2 = buf[base + 32 + i];
        buf[base + i]      = (v1 * c - v2 * s) * scale;
        buf[base + 32 + i] = (v1 * s + v2 * c) * scale;
    }
}

// ---------------------------------------------------------------------------
// gate = softmax over c of mean_t XW[b,t,C_GATE+c]; grid = BATCH, 256 threads
__global__ void gate_from_cols(const float* __restrict__ xw, float* __restrict__ gate) {
    int b = blockIdx.x;
    int t = threadIdx.x;
    __shared__ float red[3][4];
    float g0 = 0.f, g1 = 0.f, g2 = 0.f;
    for (int r = t; r < T_SEQ; r += 256) {
        const float* p = &xw[((size_t)b * T_SEQ + r) * XWW + C_GATE];
        g0 += p[0]; g1 += p[1]; g2 += p[2];
    }
    for (int off = 32; off; off >>= 1) {
        g0 += __shfl_xor(g0, off, 64);
        g1 += __shfl_xor(g1, off, 64);
        g2 += __shfl_xor(g2, off, 64);
    }
    int w = t >> 6;
    if ((t & 63) == 0) { red[0][w] = g0; red[1][w] = g1; red[2][w] = g2; }
    __syncthreads();
    if (t == 0) {
        float v0 = (red[0][0] + red[0][1] + red[0][2] + red[0][3]) / (float)T_SEQ;
        float v1 = (red[1][0] + red[1][1] + red[1][2] + red[1][3]) / (float)T_SEQ;
        float v2 = (red[2][0] + red[2][1] + red[2][2] + red[2][3]) / (float)T_SEQ;
        float m = fmaxf(v0, fmaxf(v1, v2));
        float e0 = expf(v0 - m), e1 = expf(v1 - m), e2 = expf(v2 - m);
        float s = e0 + e1 + e2;
        gate[b * 3 + 0] = e0 / s;
        gate[b * 3 + 1] = e1 / s;
        gate[b * 3 + 2] = e2 / s;
    }
}

// ---------------------------------------------------------------------------
// topk over strided score column
__global__ void topk_kernel(const float* __restrict__ base, int stride, int col,
                            int* __restrict__ idx) {
    int b = blockIdx.x;
    __shared__ float s[1024];
    __shared__ int ps[1024];
    int t = threadIdx.x;
    s[t] = base[((size_t)b * T_SEQ + t) * stride + col];
    __syncthreads();
    float mine = s[t];
    int rank = 0;
    for (int j = 0; j < 1024; j++) {
        float v = s[j];
        rank += (v > mine) || (v == mine && j < t);
    }
    int selv = (rank < KEEP) ? 1 : 0;
    ps[t] = selv;
    __syncthreads();
    for (int off = 1; off < 1024; off <<= 1) {
        int add = (t >= off) ? ps[t - off] : 0;
        __syncthreads();
        ps[t] += add;
        __syncthreads();
    }
    if (selv) idx[b * KEEP + ps[t] - 1] = t;
}

__global__ void gather_sel(const float* __restrict__ x, const int* __restrict__ idx,
                           float* __restrict__ sel) {
    for (size_t i = (size_t)blockIdx.x * blockDim.x + threadIdx.x;
         i < (size_t)BATCH * KEEP * CDIM; i += (size_t)gridDim.x * blockDim.x) {
        int c = (int)(i & (CDIM - 1));
        int r = (int)((i >> 10) & (KEEP - 1));
        int b = (int)(i >> 18);
        sel[i] = x[((size_t)b * T_SEQ + idx[b * KEEP + r]) * CDIM + c];
    }
}

// ---------------------------------------------------------------------------
// Fused 3-branch flash attention (measured-best: 403 us, LDS-instr-bound),
// reading QKV / XW / skv fused buffers.
// Grid: (T/64, NHEAD, BATCH), 512 threads. LDS 78.3 KB -> 2 blocks/CU.
// ---------------------------------------------------------------------------
__global__ __launch_bounds__(512, 4) void flash_fused(
    const float* __restrict__ qkv, const float* __restrict__ xw,
    const float* __restrict__ skv, const float* __restrict__ gate,
    float* __restrict__ out) {
    __shared__ float Qs[BQ * SK];
    __shared__ float Ks[BKT * SK];
    __shared__ float Vs[BKT * SPV];
    __shared__ float Pt[BKT * SPT];
    __shared__ float mrow[BQ], lrow[BQ], arow[BQ], mtil[BQ];

    int b = blockIdx.z, h = blockIdx.y;
    int qt = blockIdx.x;
    if (b == 1) qt = (gridDim.x - 1) - qt;   // balance causal cost across z-pairs
    int q0 = qt * BQ;
    int t = threadIdx.x;
    int tq = t >> 4, tk = t & 15;
    int qg = t >> 4, dg = t & 15;

    // stage Q tile (64 rows x 24 float4)
    for (int i = t; i < BQ * 24; i += 512) {
        int row = i / 24, d4 = i % 24;
        size_t rq = (size_t)b * T_SEQ + q0 + row;
        float4 v;
        if (d4 < 8) v = *(const float4*)&qkv[rq * QKVW + C_QN + h * 32 + d4 * 4];
        else        v = *(const float4*)&qkv[rq * QKVW + C_QR + h * 64 + (d4 - 8) * 4];
        *(float4*)&Qs[row * SK + d4 * 4] = v;
    }

    float comb[2][2] = {};
    for (int phase = 0; phase < 3; phase++) {
        bool causal = (phase != 1);
        int ntiles = causal ? (qt + 1) : (KEEP / BKT);
        float o00 = 0.f, o01 = 0.f, o10 = 0.f, o11 = 0.f;
        __syncthreads();
        if (t < BQ) { mrow[t] = -1e30f; lrow[t] = 0.f; }

        for (int kt = 0; kt < ntiles; kt++) {
            int j0 = kt * BKT;
            __syncthreads();

            // stage K tile
            for (int i = t; i < BKT * 24; i += 512) {
                int row = i / 24, d4 = i % 24;
                int j = j0 + row;
                float4 v;
                if (phase == 0) {
                    size_t rk = (size_t)b * T_SEQ + j;
                    if (d4 < 8) v = *(const float4*)&qkv[rk * QKVW + C_KN + h * 32 + d4 * 4];
                    else        v = *(const float4*)&xw[rk * XWW + C_KRO + (d4 - 8) * 4];
                } else if (phase == 1) {
                    v = *(const float4*)&skv[((size_t)b * KEEP + j) * SKW + h * 96 + d4 * 4];
                } else {
                    v = *(const float4*)&xw[((size_t)b * T_SEQ + j) * XWW + C_WINK + h * 96 + d4 * 4];
                }
                *(float4*)&Ks[row * SK + d4 * 4] = v;
            }
            // stage V tile
            for (int i = t; i < BKT * 8; i += 512) {
                int row = i >> 3, d4 = i & 7;
                int j = j0 + row;
                float4 v;
                if (phase == 0)      v = *(const float4*)&qkv[((size_t)b * T_SEQ + j) * QKVW + C_V1 + h * 32 + d4 * 4];
                else if (phase == 1) v = *(const float4*)&skv[((size_t)b * KEEP  + j) * SKW + 1536 + h * 32 + d4 * 4];
                else                 v = *(const float4*)&xw[((size_t)b * T_SEQ + j) * XWW + C_WINV + h * 32 + d4 * 4];
                *(float4*)&Vs[row * SPV + d4 * 4] = v;
            }
            __syncthreads();

            // S = Q.K^T (2q x 4k per thread)
            float s[2][4] = {};
#pragma unroll 6
            for (int d = 0; d < HEAD_D; d += 4) {
                float4 qa = *(float4*)&Qs[(2 * tq)     * SK + d];
                float4 qb = *(float4*)&Qs[(2 * tq + 1) * SK + d];
#pragma unroll
                for (int j = 0; j < 4; j++) {
                    float4 kv = *(float4*)&Ks[(16 * j + tk) * SK + d];
                    s[0][j] += qa.x * kv.x + qa.y * kv.y + qa.z * kv.z + qa.w * kv.w;
                    s[1][j] += qb.x * kv.x + qb.y * kv.y + qb.z * kv.z + qb.w * kv.w;
                }
            }
#pragma unroll
            for (int i = 0; i < 2; i++)
#pragma unroll
                for (int j = 0; j < 4; j++) {
                    int qq = q0 + 2 * tq + i;
                    int kk = j0 + 16 * j + tk;
                    float sv = s[i][j] * SCALE_ATTN;
                    if (causal && kk > qq) sv = -1e30f;
                    Pt[(16 * j + tk) * SPT + (2 * tq + i)] = sv;
                }
            __syncthreads();

            // tile row-max
            {
                int q = t >> 3, sub = t & 7;
                float mt = -1e30f;
#pragma unroll
                for (int i2 = 0; i2 < 8; i2++)
                    mt = fmaxf(mt, Pt[(sub * 8 + i2) * SPT + q]);
                mt = fmaxf(mt, __shfl_xor(mt, 1, 64));
                mt = fmaxf(mt, __shfl_xor(mt, 2, 64));
                mt = fmaxf(mt, __shfl_xor(mt, 4, 64));
                if (sub == 0) mtil[q] = mt;
            }
            __syncthreads();
            if (t < BQ) {
                float mnew = fmaxf(mrow[t], mtil[t]);
                arow[t] = __expf(mrow[t] - mnew);
                mrow[t] = mnew;
            }
            __syncthreads();
            // exponentiate + row sums
            {
                int q = t >> 3, sub = t & 7;
                float mnew = mrow[q];
                float psum = 0.f;
#pragma unroll
                for (int i2 = 0; i2 < 8; i2++) {
                    int kk = sub * 8 + i2;
                    float p = __expf(Pt[kk * SPT + q] - mnew);
                    Pt[kk * SPT + q] = p;
                    psum += p;
                }
                psum += __shfl_xor(psum, 1, 64);
                psum += __shfl_xor(psum, 2, 64);
                psum += __shfl_xor(psum, 4, 64);
                if (sub == 0) lrow[q] = lrow[q] * arow[q] + psum;
            }
            __syncthreads();

            // O accumulate (2q x 2d per thread)
            {
                float a0 = arow[2 * qg], a1 = arow[2 * qg + 1];
                o00 *= a0; o01 *= a0; o10 *= a1; o11 *= a1;
#pragma unroll 8
                for (int kk = 0; kk < BKT; kk++) {
                    float2 pv = *(float2*)&Pt[kk * SPT + 2 * qg];
                    float2 vv = *(float2*)&Vs[kk * SPV + 2 * dg];
                    o00 += pv.x * vv.x; o01 += pv.x * vv.y;
                    o10 += pv.y * vv.x; o11 += pv.y * vv.y;
                }
            }
        }  // key tiles

        // gate combine
        {
            float g = gate[b * 3 + phase];
            float i0 = g / lrow[2 * qg], i1 = g / lrow[2 * qg + 1];
            comb[0][0] += o00 * i0; comb[0][1] += o01 * i0;
            comb[1][0] += o10 * i1; comb[1][1] += o11 * i1;
        }
    }  // phases

    size_t r0 = ((size_t)b * T_SEQ + q0 + 2 * qg) * 512 + h * 32 + 2 * dg;
    out[r0]           = comb[0][0];
    out[r0 + 1]       = comb[0][1];
    out[r0 + 512]     = comb[1][0];
    out[r0 + 512 + 1] = comb[1][1];
}

// ---------------------------------------------------------------------------
extern "C" void kernel_launch(void* const* d_in, const int* in_sizes, int n_in,
                              void* d_out, int out_size, void* d_ws, size_t ws_size,
                              hipStream_t stream) {
    const float* x        = (const float*)d_in[0];
    const float* w_cq     = (const float*)d_in[1];
    const float* g_qnorm  = (const float*)d_in[2];
    const float* w_dqn    = (const float*)d_in[3];
    const float* w_dqr    = (const float*)d_in[4];
    const float* w_ckv    = (const float*)d_in[5];
    const float* g_kvnorm = (const float*)d_in[6];
    const float* w_dkn    = (const float*)d_in[7];
    const float* w_dv     = (const float*)d_in[8];
    const float* w_krope  = (const float*)d_in[9];
    const float* w_imp    = (const float*)d_in[10];
    const float* w_selk   = (const float*)d_in[11];
    const float* w_selv   = (const float*)d_in[12];
    const float* w_wink   = (const float*)d_in[13];
    const float* w_winv   = (const float*)d_in[14];
    const float* w_gate   = (const float*)d_in[15];
    const float* w_proj   = (const float*)d_in[16];
    float* out = (float*)d_out;

    const int BT = BATCH * T_SEQ;  // 2048
    const int BS = BATCH * KEEP;   // 512

    float* ws = (float*)d_ws;
    size_t o = 0;
    float* XW     = ws + o; o += (size_t)BT * XWW;     // 18.4 MB
    float* QKV    = ws + o; o += (size_t)BT * QKVW;    // 21.0 MB
    float* skv    = ws + o; o += (size_t)BS * SKW;
    float* selb   = ws + o; o += (size_t)BS * CDIM;
    float* attn   = ws + o; o += (size_t)BT * 512;
    float* Bxw    = ws + o; o += (size_t)CDIM * XWW;   // 9.2 MB
    float* Bqkv   = ws + o; o += (size_t)128 * QKVW;
    float* Bsel   = ws + o; o += (size_t)CDIM * SKW;   // 8.4 MB
    float* gatef  = ws + o; o += 8;
    int*   idx    = (int*)(ws + o); o += 512;

    auto gemm = [&](const float* A, const float* Bm, float* C, int M, int N, int K,
                    int lda, int ldb, int ldc, int ksplit = 1) {
        int kchunk = (K / ksplit + GBK - 1) / GBK * GBK;  // %16==0
        dim3 grid((N + 127) / 128, (M + 127) / 128, ksplit);
        gemm128<<<grid, 256, 0, stream>>>(A, Bm, C, M, N, K, lda, ldb, ldc, kchunk);
    };

    // zero split-K destinations (atomicAdd accumulation)
    hipMemsetAsync(skv, 0, (size_t)BS * SKW * sizeof(float), stream);
    hipMemsetAsync(out, 0, (size_t)BT * CDIM * sizeof(float), stream);

    // weight packs (independent)
    pack_xw<<<1024, 256, 0, stream>>>(Bxw, w_cq, w_ckv, w_krope, w_wink, w_winv,
                                      w_imp, w_gate);
    pack_qkv<<<128, 256, 0, stream>>>(Bqkv, w_dqn, w_dqr, w_dkn, w_dv);
    pack2<<<1024, 256, 0, stream>>>(Bsel, w_selk, 1536, w_selv, 512);

    // GEMM1: everything off x in one wide launch (grid 18x16 = 288)
    gemm(x, Bxw, XW, BT, XWW, CDIM, CDIM, XWW, XWW);

    // norms + ropes on XW slices
    rms_rows<<<BT, 64, 0, stream>>>(XW + C_CQ, g_qnorm, 96, XWW);
    rms_rows<<<BT, 64, 0, stream>>>(XW + C_CKV, g_kvnorm, 32, XWW);
    rope_inplace<<<256, 256, 0, stream>>>(XW, BT, XWW, 1, 0, C_KRO, T_SEQ, 1.0f / NHEAD);
    rope_inplace<<<2048, 256, 0, stream>>>(XW, BT, XWW, 16, 96, C_WINK + 32, T_SEQ, 1.0f);

    // gate + topk from XW columns
    gate_from_cols<<<BATCH, 256, 0, stream>>>(XW, gatef);
    topk_kernel<<<BATCH, 1024, 0, stream>>>(XW, XWW, C_IMP, idx);
    gather_sel<<<2048, 256, 0, stream>>>(x, idx, selb);

    // GEMM2: QKV = [nq|ckv] @ blockdiag (grid 20x16 = 320, K=128)
    gemm(XW, Bqkv, QKV, BT, QKVW, 128, XWW, QKVW, QKVW);
    rope_inplace<<<2048, 256, 0, stream>>>(QKV, BT, QKVW, 16, 64, C_QR, T_SEQ, 1.0f);

    // GEMM3: skv = sel @ [w_selk | w_selv], split-K 4-way (grid 16x4x4 = 256)
    gemm(selb, Bsel, skv, BS, SKW, CDIM, CDIM, SKW, SKW, 4);
    rope_inplace<<<512, 256, 0, stream>>>(skv, BS, SKW, 16, 96, 32, KEEP, 1.0f);

    // fused attention
    dim3 fgrid(T_SEQ / BQ, NHEAD, BATCH);
    flash_fused<<<fgrid, 512, 0, stream>>>(QKV, XW, skv, gatef, attn);

    // output projection, split-K 2-way (grid 8x16x2 = 256)
    gemm(attn, w_proj, out, BT, CDIM, 512, 512, CDIM, CDIM, 2);
}

// Round 9
// 978.699 us; speedup vs baseline: 2.7640x; 1.0228x over previous
//
#include <hip/hip_runtime.h>
#include <math.h>

#define T_SEQ   1024
#define BATCH   2
#define CDIM    1024
#define NHEAD   16
#define VHEAD   32
#define KEEP    256
#define HEAD_D  96   // NOPE + ROPE
#define SCALE_ATTN 0.1020620726159658f  // 1/sqrt(96)

// flash tile params
#define BQ   64
#define BKT  64
#define SK   100    // Q/K LDS row stride: 100%32=4 -> <=2-way on b128 (free)
#define SPT  66     // Pt row stride [k][q]
#define SPV  36     // V LDS row stride

// GEMM tile params: 128x128 block, 8x8 micro, single-buffered (spill-safe)
#define GBK 16
#define SA  132     // padded row stride: 132%32=4 -> <=2-way (free)

// XW layout: x @ [cq | ckv | krope | wink | winv | imp | gate]
#define XWW    2244
#define C_CQ   0      // 96
#define C_CKV  96     // 32
#define C_KRO  128    // 64
#define C_WINK 192    // 1536 (16 heads x 96)
#define C_WINV 1728   // 512  (16 heads x 32)
#define C_IMP  2240   // 1
#define C_GATE 2241   // 3

// QKV layout: [nq|ckv] @ blockdiag -> [qn | qr | kn | v1]
#define QKVW   2560
#define C_QN   0      // 512
#define C_QR   512    // 1024
#define C_KN   1536   // 512
#define C_V1   2048   // 512

#define SKW  2048   // skv: [0:1536) ks | [1536:2048) vs

// ---------------------------------------------------------------------------
// fp32 GEMM: C[M,N] = A[M,K] @ B[K,N], strides lda/ldb/ldc.
// 128x128 block, 256 threads, 8x8 micro-tile, single LDS buffer, ~95 VGPR.
// Split-K: blockIdx.z picks K-chunk; gridDim.z>1 -> atomicAdd (C zeroed).
// ---------------------------------------------------------------------------
__global__ __launch_bounds__(256) void gemm128(const float* __restrict__ A,
                                               const float* __restrict__ B,
                                               float* __restrict__ C,
                                               int M, int N, int K,
                                               int lda, int ldb, int ldc,
                                               int kchunk) {
    __shared__ float As[GBK][SA];   // [k][m] transposed A tile
    __shared__ float Bs[GBK][SA];   // [k][n]
    int t = threadIdx.x;
    int tx = t & 15, ty = t >> 4;
    int row0 = blockIdx.y * 128, col0 = blockIdx.x * 128;
    int kb = blockIdx.z * kchunk;
    int ke = min(K, kb + kchunk);
    float acc[8][8] = {};

    for (int k0 = kb; k0 < ke; k0 += GBK) {
#pragma unroll
        for (int r = 0; r < 2; r++) {
            int idx = t + 256 * r;            // 0..511
            int row = idx >> 2, k4 = idx & 3;
            int gr = row0 + row;
            float4 v = make_float4(0.f, 0.f, 0.f, 0.f);
            if (gr < M) v = *(const float4*)&A[(size_t)gr * lda + k0 + k4 * 4];
            As[k4 * 4 + 0][row] = v.x;
            As[k4 * 4 + 1][row] = v.y;
            As[k4 * 4 + 2][row] = v.z;
            As[k4 * 4 + 3][row] = v.w;
        }
#pragma unroll
        for (int r = 0; r < 2; r++) {
            int idx = t + 256 * r;
            int kk = idx >> 5, n4 = idx & 31;
            int gc = col0 + n4 * 4;
            float4 v = make_float4(0.f, 0.f, 0.f, 0.f);
            if (gc + 3 < N) {
                v = *(const float4*)&B[(size_t)(k0 + kk) * ldb + gc];
            } else if (gc < N) {
                const float* bp = &B[(size_t)(k0 + kk) * ldb];
                float tmp[4] = {0.f, 0.f, 0.f, 0.f};
                for (int j = 0; j < 4 && gc + j < N; j++) tmp[j] = bp[gc + j];
                v = make_float4(tmp[0], tmp[1], tmp[2], tmp[3]);
            }
            *(float4*)&Bs[kk][n4 * 4] = v;
        }
        __syncthreads();
#pragma unroll
        for (int kk = 0; kk < GBK; kk++) {
            float4 a0 = *(float4*)&As[kk][ty * 4];
            float4 a1 = *(float4*)&As[kk][64 + ty * 4];
            float4 b0 = *(float4*)&Bs[kk][tx * 4];
            float4 b1 = *(float4*)&Bs[kk][64 + tx * 4];
            float av[8] = {a0.x, a0.y, a0.z, a0.w, a1.x, a1.y, a1.z, a1.w};
            float bv[8] = {b0.x, b0.y, b0.z, b0.w, b1.x, b1.y, b1.z, b1.w};
#pragma unroll
            for (int i = 0; i < 8; i++)
#pragma unroll
                for (int j = 0; j < 8; j++) acc[i][j] += av[i] * bv[j];
        }
        __syncthreads();
    }

    bool split = (gridDim.z > 1);
#pragma unroll
    for (int i = 0; i < 8; i++) {
        int gr = row0 + ((i < 4) ? (ty * 4 + i) : (64 + ty * 4 + (i - 4)));
        if (gr >= M) continue;
#pragma unroll
        for (int half = 0; half < 2; half++) {
            int gc = col0 + half * 64 + tx * 4;
            if (gc + 3 >= N) continue;
            float* cp = &C[(size_t)gr * ldc + gc];
            if (split) {
                atomicAdd(cp + 0, acc[i][half * 4 + 0]);
                atomicAdd(cp + 1, acc[i][half * 4 + 1]);
                atomicAdd(cp + 2, acc[i][half * 4 + 2]);
                atomicAdd(cp + 3, acc[i][half * 4 + 3]);
            } else {
                *(float4*)cp = make_float4(acc[i][half * 4 + 0], acc[i][half * 4 + 1],
                                           acc[i][half * 4 + 2], acc[i][half * 4 + 3]);
            }
        }
    }
}

// ---------------------------------------------------------------------------
// pack the 7-way x-side weight concat
__global__ void pack_xw(float* __restrict__ dst,
                        const float* __restrict__ cq, const float* __restrict__ ckv,
                        const float* __restrict__ kro, const float* __restrict__ wink,
                        const float* __restrict__ winv, const float* __restrict__ imp,
                        const float* __restrict__ gate) {
    int r = blockIdx.x;
    for (int c = threadIdx.x; c < XWW; c += blockDim.x) {
        float v;
        if      (c < C_CKV)  v = cq  [(size_t)r * 96   + c];
        else if (c < C_KRO)  v = ckv [(size_t)r * 32   + (c - C_CKV)];
        else if (c < C_WINK) v = kro [(size_t)r * 64   + (c - C_KRO)];
        else if (c < C_WINV) v = wink[(size_t)r * 1536 + (c - C_WINK)];
        else if (c < C_IMP)  v = winv[(size_t)r * 512  + (c - C_WINV)];
        else if (c < C_GATE) v = imp [(size_t)r * 1    + (c - C_IMP)];
        else                 v = gate[(size_t)r * 3    + (c - C_GATE)];
        dst[(size_t)r * XWW + c] = v;
    }
}

// block-diagonal pack: rows 0..95 = [dqn 512 | dqr 1024 | 0 | 0],
// rows 96..127 = [0 | 0 | dkn 512 | dv 512]; dst 128 x 2560
__global__ void pack_qkv(float* __restrict__ dst,
                         const float* __restrict__ dqn, const float* __restrict__ dqr,
                         const float* __restrict__ dkn, const float* __restrict__ dv) {
    int r = blockIdx.x;
    for (int c = threadIdx.x; c < QKVW; c += blockDim.x) {
        float v = 0.f;
        if (r < 96) {
            if (c < C_QR)      v = dqn[(size_t)r * 512 + c];
            else if (c < C_KN) v = dqr[(size_t)r * 1024 + (c - C_QR)];
        } else {
            if (c >= C_KN && c < C_V1) v = dkn[(size_t)(r - 96) * 512 + (c - C_KN)];
            else if (c >= C_V1)        v = dv [(size_t)(r - 96) * 512 + (c - C_V1)];
        }
        dst[(size_t)r * QKVW + c] = v;
    }
}

// pack2: dst[r] = [s0[r] | s1[r]]
__global__ void pack2(float* __restrict__ dst,
                      const float* __restrict__ s0, int w0,
                      const float* __restrict__ s1, int w1) {
    int W = w0 + w1;
    int r = blockIdx.x;
    for (int c = threadIdx.x; c < W; c += blockDim.x) {
        float v = (c < w0) ? s0[(size_t)r * w0 + c] : s1[(size_t)r * w1 + (c - w0)];
        dst[(size_t)r * W + c] = v;
    }
}

// ---------------------------------------------------------------------------
__global__ void rms_rows(float* __restrict__ buf, const float* __restrict__ g,
                         int D, int stride) {
    int row = blockIdx.x;
    int lane = threadIdx.x;  // blockDim = 64
    float* rp = buf + (size_t)row * stride;
    float ss = 0.f;
    for (int d = lane; d < D; d += 64) {
        float v = rp[d];
        ss += v * v;
    }
    for (int off = 32; off; off >>= 1) ss += __shfl_xor(ss, off, 64);
    float r = rsqrtf(ss / (float)D + 1e-6f);
    for (int d = lane; d < D; d += 64) rp[d] *= r * g[d];
}

// ---------------------------------------------------------------------------
__global__ void rope_inplace(float* __restrict__ buf, int nrows, int rstride,
                             int nheads, int hstride, int roff, int posmod,
                             float scale) {
    int total = nrows * nheads * 32;
    for (int it = blockIdx.x * blockDim.x + threadIdx.x; it < total;
         it += gridDim.x * blockDim.x) {
        int i = it & 31;
        int hr = it >> 5;
        int h = hr % nheads;
        int row = hr / nheads;
        int pos = row % posmod;
        float expo = (float)i * (1.0f / 32.0f);
        float f = 1.0f / powf(10000.0f, expo);
        float a = (float)pos * f;
        float s, c;
        sincosf(a, &s, &c);
        size_t base = (size_t)row * rstride + (size_t)h * hstride + roff;
        float v1 = buf[base + i], v2 = buf[base + 32 + i];
        buf[base + i]      = (v1 * c - v2 * s) * scale;
        buf[base + 32 + i] = (v1 * s + v2 * c) * scale;
    }
}

// ---------------------------------------------------------------------------
// gate = softmax over c of mean_t XW[b,t,C_GATE+c]; grid = BATCH, 256 threads
__global__ void gate_from_cols(const float* __restrict__ xw, float* __restrict__ gate) {
    int b = blockIdx.x;
    int t = threadIdx.x;
    __shared__ float red[3][4];
    float g0 = 0.f, g1 = 0.f, g2 = 0.f;
    for (int r = t; r < T_SEQ; r += 256) {
        const float* p = &xw[((size_t)b * T_SEQ + r) * XWW + C_GATE];
        g0 += p[0]; g1 += p[1]; g2 += p[2];
    }
    for (int off = 32; off; off >>= 1) {
        g0 += __shfl_xor(g0, off, 64);
        g1 += __shfl_xor(g1, off, 64);
        g2 += __shfl_xor(g2, off, 64);
    }
    int w = t >> 6;
    if ((t & 63) == 0) { red[0][w] = g0; red[1][w] = g1; red[2][w] = g2; }
    __syncthreads();
    if (t == 0) {
        float v0 = (red[0][0] + red[0][1] + red[0][2] + red[0][3]) / (float)T_SEQ;
        float v1 = (red[1][0] + red[1][1] + red[1][2] + red[1][3]) / (float)T_SEQ;
        float v2 = (red[2][0] + red[2][1] + red[2][2] + red[2][3]) / (float)T_SEQ;
        float m = fmaxf(v0, fmaxf(v1, v2));
        float e0 = expf(v0 - m), e1 = expf(v1 - m), e2 = expf(v2 - m);
        float s = e0 + e1 + e2;
        gate[b * 3 + 0] = e0 / s;
        gate[b * 3 + 1] = e1 / s;
        gate[b * 3 + 2] = e2 / s;
    }
}

// ---------------------------------------------------------------------------
// topk over strided score column
__global__ void topk_kernel(const float* __restrict__ base, int stride, int col,
                            int* __restrict__ idx) {
    int b = blockIdx.x;
    __shared__ float s[1024];
    __shared__ int ps[1024];
    int t = threadIdx.x;
    s[t] = base[((size_t)b * T_SEQ + t) * stride + col];
    __syncthreads();
    float mine = s[t];
    int rank = 0;
    for (int j = 0; j < 1024; j++) {
        float v = s[j];
        rank += (v > mine) || (v == mine && j < t);
    }
    int selv = (rank < KEEP) ? 1 : 0;
    ps[t] = selv;
    __syncthreads();
    for (int off = 1; off < 1024; off <<= 1) {
        int add = (t >= off) ? ps[t - off] : 0;
        __syncthreads();
        ps[t] += add;
        __syncthreads();
    }
    if (selv) idx[b * KEEP + ps[t] - 1] = t;
}

__global__ void gather_sel(const float* __restrict__ x, const int* __restrict__ idx,
                           float* __restrict__ sel) {
    for (size_t i = (size_t)blockIdx.x * blockDim.x + threadIdx.x;
         i < (size_t)BATCH * KEEP * CDIM; i += (size_t)gridDim.x * blockDim.x) {
        int c = (int)(i & (CDIM - 1));
        int r = (int)((i >> 10) & (KEEP - 1));
        int b = (int)(i >> 18);
        sel[i] = x[((size_t)b * T_SEQ + idx[b * KEEP + r]) * CDIM + c];
    }
}

// ---------------------------------------------------------------------------
// Fused 3-branch flash attention v5: register-resident online softmax.
// The 16-lane group (tq = t>>4) owns rows 2tq,2tq+1 end-to-end: S slice in
// regs -> shfl row-max/row-sum -> m,l,alpha in regs -> exp'd P written ONCE
// to Pt (float2) -> PV by the SAME group (qg==tq), so Pt visibility is
// intra-wave (DS pipe in-order per wave) and needs no barrier.
// Only 2 barriers per tile (around K/V staging). Accumulators stay 4 regs —
// this is NOT the round-1 rewrite (o stayed distributed there; here PV and
// its LDS transpose via Pt are unchanged, only the softmax LDS traffic and
// 4 barriers are removed).
// Grid: (T/64, NHEAD, BATCH), 512 threads. LDS 77.3 KB -> 2 blocks/CU.
// ---------------------------------------------------------------------------
__global__ __launch_bounds__(512, 4) void flash_fused(
    const float* __restrict__ qkv, const float* __restrict__ xw,
    const float* __restrict__ skv, const float* __restrict__ gate,
    float* __restrict__ out) {
    __shared__ float Qs[BQ * SK];
    __shared__ float Ks[BKT * SK];
    __shared__ float Vs[BKT * SPV];
    __shared__ float Pt[BKT * SPT];

    int b = blockIdx.z, h = blockIdx.y;
    int qt = blockIdx.x;
    if (b == 1) qt = (gridDim.x - 1) - qt;   // balance causal cost across z-pairs
    int q0 = qt * BQ;
    int t = threadIdx.x;
    int tq = t >> 4, tk = t & 15;   // S: q=2*tq+i, k=16*j+tk; PV: q=2*tq+i, d=2*tk+j

    // stage Q tile (64 rows x 24 float4)
    for (int i = t; i < BQ * 24; i += 512) {
        int row = i / 24, d4 = i % 24;
        size_t rq = (size_t)b * T_SEQ + q0 + row;
        float4 v;
        if (d4 < 8) v = *(const float4*)&qkv[rq * QKVW + C_QN + h * 32 + d4 * 4];
        else        v = *(const float4*)&qkv[rq * QKVW + C_QR + h * 64 + (d4 - 8) * 4];
        *(float4*)&Qs[row * SK + d4 * 4] = v;
    }

    int qq0 = q0 + 2 * tq, qq1 = qq0 + 1;
    float comb[2][2] = {};
    for (int phase = 0; phase < 3; phase++) {
        bool causal = (phase != 1);
        int ntiles = causal ? (qt + 1) : (KEEP / BKT);
        float m0 = -1e30f, m1 = -1e30f, l0 = 0.f, l1 = 0.f;
        float o00 = 0.f, o01 = 0.f, o10 = 0.f, o11 = 0.f;

        for (int kt = 0; kt < ntiles; kt++) {
            int j0 = kt * BKT;
            __syncthreads();  // all waves done reading Ks/Vs of prev tile (covers Qs 1st time)

            // stage K tile (64 rows x 24 float4)
            for (int i = t; i < BKT * 24; i += 512) {
                int row = i / 24, d4 = i % 24;
                int j = j0 + row;
                float4 v;
                if (phase == 0) {
                    size_t rk = (size_t)b * T_SEQ + j;
                    if (d4 < 8) v = *(const float4*)&qkv[rk * QKVW + C_KN + h * 32 + d4 * 4];
                    else        v = *(const float4*)&xw[rk * XWW + C_KRO + (d4 - 8) * 4];
                } else if (phase == 1) {
                    v = *(const float4*)&skv[((size_t)b * KEEP + j) * SKW + h * 96 + d4 * 4];
                } else {
                    v = *(const float4*)&xw[((size_t)b * T_SEQ + j) * XWW + C_WINK + h * 96 + d4 * 4];
                }
                *(float4*)&Ks[row * SK + d4 * 4] = v;
            }
            // stage V tile (64 rows x 8 float4)
            for (int i = t; i < BKT * 8; i += 512) {
                int row = i >> 3, d4 = i & 7;
                int j = j0 + row;
                float4 v;
                if (phase == 0)      v = *(const float4*)&qkv[((size_t)b * T_SEQ + j) * QKVW + C_V1 + h * 32 + d4 * 4];
                else if (phase == 1) v = *(const float4*)&skv[((size_t)b * KEEP  + j) * SKW + 1536 + h * 32 + d4 * 4];
                else                 v = *(const float4*)&xw[((size_t)b * T_SEQ + j) * XWW + C_WINV + h * 32 + d4 * 4];
                *(float4*)&Vs[row * SPV + d4 * 4] = v;
            }
            __syncthreads();

            // S = Q.K^T (2q x 4k per thread), registers
            float s0[4] = {}, s1[4] = {};
#pragma unroll 6
            for (int d = 0; d < HEAD_D; d += 4) {
                float4 qa = *(float4*)&Qs[(2 * tq)     * SK + d];
                float4 qb = *(float4*)&Qs[(2 * tq + 1) * SK + d];
#pragma unroll
                for (int j = 0; j < 4; j++) {
                    float4 kv = *(float4*)&Ks[(16 * j + tk) * SK + d];
                    s0[j] += qa.x * kv.x + qa.y * kv.y + qa.z * kv.z + qa.w * kv.w;
                    s1[j] += qb.x * kv.x + qb.y * kv.y + qb.z * kv.z + qb.w * kv.w;
                }
            }
            // scale + mask + tile row-max (4 local + 4 shfl over 16-lane group)
            float mt0 = -1e30f, mt1 = -1e30f;
#pragma unroll
            for (int j = 0; j < 4; j++) {
                int kk = j0 + 16 * j + tk;
                s0[j] *= SCALE_ATTN;
                s1[j] *= SCALE_ATTN;
                if (causal && kk > qq0) s0[j] = -1e30f;
                if (causal && kk > qq1) s1[j] = -1e30f;
                mt0 = fmaxf(mt0, s0[j]);
                mt1 = fmaxf(mt1, s1[j]);
            }
#pragma unroll
            for (int off = 1; off <= 8; off <<= 1) {
                mt0 = fmaxf(mt0, __shfl_xor(mt0, off, 64));
                mt1 = fmaxf(mt1, __shfl_xor(mt1, off, 64));
            }
            float mn0 = fmaxf(m0, mt0), mn1 = fmaxf(m1, mt1);
            float a0 = __expf(m0 - mn0), a1 = __expf(m1 - mn1);
            m0 = mn0; m1 = mn1;

            // exponentiate in regs, write P once (float2), row-sum via shfl
            float rs0 = 0.f, rs1 = 0.f;
#pragma unroll
            for (int j = 0; j < 4; j++) {
                float p0 = __expf(s0[j] - mn0);
                float p1 = __expf(s1[j] - mn1);
                rs0 += p0; rs1 += p1;
                *(float2*)&Pt[(16 * j + tk) * SPT + 2 * tq] = make_float2(p0, p1);
            }
#pragma unroll
            for (int off = 1; off <= 8; off <<= 1) {
                rs0 += __shfl_xor(rs0, off, 64);
                rs1 += __shfl_xor(rs1, off, 64);
            }
            l0 = l0 * a0 + rs0;
            l1 = l1 * a1 + rs1;

            // PV (2q x 2d per thread). Pt cols 2tq,2tq+1 were written by this
            // same wave (same 16-lane group) -> DS in-order per wave, no barrier.
            o00 *= a0; o01 *= a0; o10 *= a1; o11 *= a1;
#pragma unroll 8
            for (int kk = 0; kk < BKT; kk++) {
                float2 pv = *(float2*)&Pt[kk * SPT + 2 * tq];
                float2 vv = *(float2*)&Vs[kk * SPV + 2 * tk];
                o00 += pv.x * vv.x; o01 += pv.x * vv.y;
                o10 += pv.y * vv.x; o11 += pv.y * vv.y;
            }
        }  // key tiles

        // gate combine (m,l live in registers, replicated within the group)
        float g = gate[b * 3 + phase];
        float i0 = g / l0, i1 = g / l1;
        comb[0][0] += o00 * i0; comb[0][1] += o01 * i0;
        comb[1][0] += o10 * i1; comb[1][1] += o11 * i1;
    }  // phases

    size_t r0 = ((size_t)b * T_SEQ + q0 + 2 * tq) * 512 + h * 32 + 2 * tk;
    out[r0]           = comb[0][0];
    out[r0 + 1]       = comb[0][1];
    out[r0 + 512]     = comb[1][0];
    out[r0 + 512 + 1] = comb[1][1];
}

// ---------------------------------------------------------------------------
extern "C" void kernel_launch(void* const* d_in, const int* in_sizes, int n_in,
                              void* d_out, int out_size, void* d_ws, size_t ws_size,
                              hipStream_t stream) {
    const float* x        = (const float*)d_in[0];
    const float* w_cq     = (const float*)d_in[1];
    const float* g_qnorm  = (const float*)d_in[2];
    const float* w_dqn    = (const float*)d_in[3];
    const float* w_dqr    = (const float*)d_in[4];
    const float* w_ckv    = (const float*)d_in[5];
    const float* g_kvnorm = (const float*)d_in[6];
    const float* w_dkn    = (const float*)d_in[7];
    const float* w_dv     = (const float*)d_in[8];
    const float* w_krope  = (const float*)d_in[9];
    const float* w_imp    = (const float*)d_in[10];
    const float* w_selk   = (const float*)d_in[11];
    const float* w_selv   = (const float*)d_in[12];
    const float* w_wink   = (const float*)d_in[13];
    const float* w_winv   = (const float*)d_in[14];
    const float* w_gate   = (const float*)d_in[15];
    const float* w_proj   = (const float*)d_in[16];
    float* out = (float*)d_out;

    const int BT = BATCH * T_SEQ;  // 2048
    const int BS = BATCH * KEEP;   // 512

    float* ws = (float*)d_ws;
    size_t o = 0;
    float* XW     = ws + o; o += (size_t)BT * XWW;     // 18.4 MB
    float* QKV    = ws + o; o += (size_t)BT * QKVW;    // 21.0 MB
    float* skv    = ws + o; o += (size_t)BS * SKW;
    float* selb   = ws + o; o += (size_t)BS * CDIM;
    float* attn   = ws + o; o += (size_t)BT * 512;
    float* Bxw    = ws + o; o += (size_t)CDIM * XWW;   // 9.2 MB
    float* Bqkv   = ws + o; o += (size_t)128 * QKVW;
    float* Bsel   = ws + o; o += (size_t)CDIM * SKW;   // 8.4 MB
    float* gatef  = ws + o; o += 8;
    int*   idx    = (int*)(ws + o); o += 512;

    auto gemm = [&](const float* A, const float* Bm, float* C, int M, int N, int K,
                    int lda, int ldb, int ldc, int ksplit = 1) {
        int kchunk = (K / ksplit + GBK - 1) / GBK * GBK;  // %16==0
        dim3 grid((N + 127) / 128, (M + 127) / 128, ksplit);
        gemm128<<<grid, 256, 0, stream>>>(A, Bm, C, M, N, K, lda, ldb, ldc, kchunk);
    };

    // zero split-K destinations (atomicAdd accumulation)
    hipMemsetAsync(skv, 0, (size_t)BS * SKW * sizeof(float), stream);
    hipMemsetAsync(out, 0, (size_t)BT * CDIM * sizeof(float), stream);

    // weight packs (independent)
    pack_xw<<<1024, 256, 0, stream>>>(Bxw, w_cq, w_ckv, w_krope, w_wink, w_winv,
                                      w_imp, w_gate);
    pack_qkv<<<128, 256, 0, stream>>>(Bqkv, w_dqn, w_dqr, w_dkn, w_dv);
    pack2<<<1024, 256, 0, stream>>>(Bsel, w_selk, 1536, w_selv, 512);

    // GEMM1: everything off x in one wide launch (grid 18x16 = 288)
    gemm(x, Bxw, XW, BT, XWW, CDIM, CDIM, XWW, XWW);

    // norms + ropes on XW slices
    rms_rows<<<BT, 64, 0, stream>>>(XW + C_CQ, g_qnorm, 96, XWW);
    rms_rows<<<BT, 64, 0, stream>>>(XW + C_CKV, g_kvnorm, 32, XWW);
    rope_inplace<<<256, 256, 0, stream>>>(XW, BT, XWW, 1, 0, C_KRO, T_SEQ, 1.0f / NHEAD);
    rope_inplace<<<2048, 256, 0, stream>>>(XW, BT, XWW, 16, 96, C_WINK + 32, T_SEQ, 1.0f);

    // gate + topk from XW columns
    gate_from_cols<<<BATCH, 256, 0, stream>>>(XW, gatef);
    topk_kernel<<<BATCH, 1024, 0, stream>>>(XW, XWW, C_IMP, idx);
    gather_sel<<<2048, 256, 0, stream>>>(x, idx, selb);

    // GEMM2: QKV = [nq|ckv] @ blockdiag (grid 20x16 = 320, K=128)
    gemm(XW, Bqkv, QKV, BT, QKVW, 128, XWW, QKVW, QKVW);
    rope_inplace<<<2048, 256, 0, stream>>>(QKV, BT, QKVW, 16, 64, C_QR, T_SEQ, 1.0f);

    // GEMM3: skv = sel @ [w_selk | w_selv], split-K 4-way (grid 16x4x4 = 256)
    gemm(selb, Bsel, skv, BS, SKW, CDIM, CDIM, SKW, SKW, 4);
    rope_inplace<<<512, 256, 0, stream>>>(skv, BS, SKW, 16, 96, 32, KEEP, 1.0f);

    // fused attention
    dim3 fgrid(T_SEQ / BQ, NHEAD, BATCH);
    flash_fused<<<fgrid, 512, 0, stream>>>(QKV, XW, skv, gatef, attn);

    // output projection, split-K 2-way (grid 8x16x2 = 256)
    gemm(attn, w_proj, out, BT, CDIM, 512, 512, CDIM, CDIM, 2);
}

// Round 10
// 955.545 us; speedup vs baseline: 2.8310x; 1.0242x over previous
//
#include <hip/hip_runtime.h>
#include <math.h>

#define T_SEQ   1024
#define BATCH   2
#define CDIM    1024
#define NHEAD   16
#define VHEAD   32
#define KEEP    256
#define HEAD_D  96   // NOPE + ROPE
#define SCALE_ATTN 0.1020620726159658f  // 1/sqrt(96)

// flash tile params
#define BQ   64
#define BKT  64
#define SK   100    // Q/K LDS row stride: 100%32=4 -> <=2-way on b128 (free)
#define SPT  66     // Pt row stride [k][q]
#define SPV  36     // V LDS row stride

// GEMM tile params: 128x128 block, 8x8 micro, single-buffered (spill-safe)
#define GBK 16
#define SA  132     // padded row stride: 132%32=4 -> <=2-way (free)

// XW layout: x @ [cq | ckv | krope | wink | winv | imp | gate]
#define XWW    2244
#define C_CQ   0      // 96
#define C_CKV  96     // 32
#define C_KRO  128    // 64
#define C_WINK 192    // 1536 (16 heads x 96)
#define C_WINV 1728   // 512  (16 heads x 32)
#define C_IMP  2240   // 1
#define C_GATE 2241   // 3

// QKV layout: [nq|ckv] @ blockdiag -> [qn | qr | kn | v1]
#define QKVW   2560
#define C_QN   0      // 512
#define C_QR   512    // 1024
#define C_KN   1536   // 512
#define C_V1   2048   // 512

#define SKW  2048   // skv: [0:1536) ks | [1536:2048) vs

// ---------------------------------------------------------------------------
// fp32 GEMM: C[M,N] = A[M,K] @ B[K,N], strides lda/ldb/ldc.
// 128x128 block, 256 threads, 8x8 micro-tile, single LDS buffer, ~95 VGPR.
// Split-K: blockIdx.z picks K-chunk; gridDim.z>1 -> atomicAdd (C zeroed).
// ---------------------------------------------------------------------------
__global__ __launch_bounds__(256) void gemm128(const float* __restrict__ A,
                                               const float* __restrict__ B,
                                               float* __restrict__ C,
                                               int M, int N, int K,
                                               int lda, int ldb, int ldc,
                                               int kchunk) {
    __shared__ float As[GBK][SA];   // [k][m] transposed A tile
    __shared__ float Bs[GBK][SA];   // [k][n]
    int t = threadIdx.x;
    int tx = t & 15, ty = t >> 4;
    int row0 = blockIdx.y * 128, col0 = blockIdx.x * 128;
    int kb = blockIdx.z * kchunk;
    int ke = min(K, kb + kchunk);
    float acc[8][8] = {};

    for (int k0 = kb; k0 < ke; k0 += GBK) {
#pragma unroll
        for (int r = 0; r < 2; r++) {
            int idx = t + 256 * r;            // 0..511
            int row = idx >> 2, k4 = idx & 3;
            int gr = row0 + row;
            float4 v = make_float4(0.f, 0.f, 0.f, 0.f);
            if (gr < M) v = *(const float4*)&A[(size_t)gr * lda + k0 + k4 * 4];
            As[k4 * 4 + 0][row] = v.x;
            As[k4 * 4 + 1][row] = v.y;
            As[k4 * 4 + 2][row] = v.z;
            As[k4 * 4 + 3][row] = v.w;
        }
#pragma unroll
        for (int r = 0; r < 2; r++) {
            int idx = t + 256 * r;
            int kk = idx >> 5, n4 = idx & 31;
            int gc = col0 + n4 * 4;
            float4 v = make_float4(0.f, 0.f, 0.f, 0.f);
            if (gc + 3 < N) {
                v = *(const float4*)&B[(size_t)(k0 + kk) * ldb + gc];
            } else if (gc < N) {
                const float* bp = &B[(size_t)(k0 + kk) * ldb];
                float tmp[4] = {0.f, 0.f, 0.f, 0.f};
                for (int j = 0; j < 4 && gc + j < N; j++) tmp[j] = bp[gc + j];
                v = make_float4(tmp[0], tmp[1], tmp[2], tmp[3]);
            }
            *(float4*)&Bs[kk][n4 * 4] = v;
        }
        __syncthreads();
#pragma unroll
        for (int kk = 0; kk < GBK; kk++) {
            float4 a0 = *(float4*)&As[kk][ty * 4];
            float4 a1 = *(float4*)&As[kk][64 + ty * 4];
            float4 b0 = *(float4*)&Bs[kk][tx * 4];
            float4 b1 = *(float4*)&Bs[kk][64 + tx * 4];
            float av[8] = {a0.x, a0.y, a0.z, a0.w, a1.x, a1.y, a1.z, a1.w};
            float bv[8] = {b0.x, b0.y, b0.z, b0.w, b1.x, b1.y, b1.z, b1.w};
#pragma unroll
            for (int i = 0; i < 8; i++)
#pragma unroll
                for (int j = 0; j < 8; j++) acc[i][j] += av[i] * bv[j];
        }
        __syncthreads();
    }

    bool split = (gridDim.z > 1);
#pragma unroll
    for (int i = 0; i < 8; i++) {
        int gr = row0 + ((i < 4) ? (ty * 4 + i) : (64 + ty * 4 + (i - 4)));
        if (gr >= M) continue;
#pragma unroll
        for (int half = 0; half < 2; half++) {
            int gc = col0 + half * 64 + tx * 4;
            if (gc + 3 >= N) continue;
            float* cp = &C[(size_t)gr * ldc + gc];
            if (split) {
                atomicAdd(cp + 0, acc[i][half * 4 + 0]);
                atomicAdd(cp + 1, acc[i][half * 4 + 1]);
                atomicAdd(cp + 2, acc[i][half * 4 + 2]);
                atomicAdd(cp + 3, acc[i][half * 4 + 3]);
            } else {
                *(float4*)cp = make_float4(acc[i][half * 4 + 0], acc[i][half * 4 + 1],
                                           acc[i][half * 4 + 2], acc[i][half * 4 + 3]);
            }
        }
    }
}

// ---------------------------------------------------------------------------
// rope cos/sin table: tab[pos*32+i] = (cos(pos*f_i), sin(pos*f_i)),
// f_i = 1/10000^(i/32) — identical fp32 math to the original rope kernels.
__global__ void build_tab(float2* __restrict__ tab) {
    int idx = blockIdx.x * blockDim.x + threadIdx.x;   // 64 x 512 = 32768
    if (idx >= T_SEQ * 32) return;
    int pos = idx >> 5, i = idx & 31;
    float expo = (float)i * (1.0f / 32.0f);
    float f = 1.0f / powf(10000.0f, expo);
    float a = (float)pos * f;
    float s, c;
    sincosf(a, &s, &c);
    tab[idx] = make_float2(c, s);
}

// ---------------------------------------------------------------------------
// merged weight pack: blocks [0,1024) -> Bxw rows, [1024,1152) -> Bqkv rows,
// [1152,2176) -> Bsel rows.
__global__ void pack_all(float* __restrict__ Bxw, float* __restrict__ Bqkv,
                         float* __restrict__ Bsel,
                         const float* __restrict__ cq, const float* __restrict__ ckv,
                         const float* __restrict__ kro, const float* __restrict__ wink,
                         const float* __restrict__ winv, const float* __restrict__ imp,
                         const float* __restrict__ gate,
                         const float* __restrict__ dqn, const float* __restrict__ dqr,
                         const float* __restrict__ dkn, const float* __restrict__ dv,
                         const float* __restrict__ selk, const float* __restrict__ selv) {
    int blk = blockIdx.x;
    if (blk < 1024) {
        int r = blk;
        for (int c = threadIdx.x; c < XWW; c += blockDim.x) {
            float v;
            if      (c < C_CKV)  v = cq  [(size_t)r * 96   + c];
            else if (c < C_KRO)  v = ckv [(size_t)r * 32   + (c - C_CKV)];
            else if (c < C_WINK) v = kro [(size_t)r * 64   + (c - C_KRO)];
            else if (c < C_WINV) v = wink[(size_t)r * 1536 + (c - C_WINK)];
            else if (c < C_IMP)  v = winv[(size_t)r * 512  + (c - C_WINV)];
            else if (c < C_GATE) v = imp [(size_t)r * 1    + (c - C_IMP)];
            else                 v = gate[(size_t)r * 3    + (c - C_GATE)];
            Bxw[(size_t)r * XWW + c] = v;
        }
    } else if (blk < 1152) {
        int r = blk - 1024;
        for (int c = threadIdx.x; c < QKVW; c += blockDim.x) {
            float v = 0.f;
            if (r < 96) {
                if (c < C_QR)      v = dqn[(size_t)r * 512 + c];
                else if (c < C_KN) v = dqr[(size_t)r * 1024 + (c - C_QR)];
            } else {
                if (c >= C_KN && c < C_V1) v = dkn[(size_t)(r - 96) * 512 + (c - C_KN)];
                else if (c >= C_V1)        v = dv [(size_t)(r - 96) * 512 + (c - C_V1)];
            }
            Bqkv[(size_t)r * QKVW + c] = v;
        }
    } else {
        int r = blk - 1152;
        for (int c = threadIdx.x; c < SKW; c += blockDim.x) {
            float v = (c < 1536) ? selk[(size_t)r * 1536 + c]
                                 : selv[(size_t)r * 512 + (c - 1536)];
            Bsel[(size_t)r * SKW + c] = v;
        }
    }
}

// ---------------------------------------------------------------------------
// fused post-XW row pass: rms(cq), rms(ckv), rope(kro, scale 1/16),
// rope(wink heads). One block per row, 256 threads; slices are disjoint so
// no intra-block sync is needed. Waves 0..2 own the small slices; all
// threads then handle the 512 wink items.
__global__ void xw_post(float* __restrict__ XW, const float* __restrict__ gq,
                        const float* __restrict__ gkv,
                        const float2* __restrict__ tab) {
    int row = blockIdx.x;
    int t = threadIdx.x;
    int w = t >> 6, lane = t & 63;
    float* rp = XW + (size_t)row * XWW;
    int pos = row & (T_SEQ - 1);
    const float2* tp = tab + pos * 32;

    if (w == 0) {                      // rms over cols [0,96)
        float ss = 0.f;
        for (int d = lane; d < 96; d += 64) { float v = rp[d]; ss += v * v; }
        for (int off = 32; off; off >>= 1) ss += __shfl_xor(ss, off, 64);
        float r = rsqrtf(ss / 96.0f + 1e-6f);
        for (int d = lane; d < 96; d += 64) rp[d] *= r * gq[d];
    } else if (w == 1) {               // rms over cols [96,128)
        float ss = 0.f;
        for (int d = lane; d < 32; d += 64) { float v = rp[C_CKV + d]; ss += v * v; }
        for (int off = 32; off; off >>= 1) ss += __shfl_xor(ss, off, 64);
        float r = rsqrtf(ss / 32.0f + 1e-6f);
        for (int d = lane; d < 32; d += 64) rp[C_CKV + d] *= r * gkv[d];
    } else if (w == 2) {               // rope kro cols [128,192), scale 1/16
        if (lane < 32) {
            float2 cs = tp[lane];
            float v1 = rp[C_KRO + lane], v2 = rp[C_KRO + 32 + lane];
            rp[C_KRO + lane]      = (v1 * cs.x - v2 * cs.y) * (1.0f / NHEAD);
            rp[C_KRO + 32 + lane] = (v1 * cs.y + v2 * cs.x) * (1.0f / NHEAD);
        }
    }
    // wink rope: 16 heads x 32 items, all 256 threads, 2 items each
#pragma unroll
    for (int j = 0; j < 2; j++) {
        int item = t + j * 256;        // 0..511
        int h = item >> 5, i = item & 31;
        float2 cs = tp[i];
        size_t base = (size_t)(C_WINK + 32) + h * 96;
        float v1 = rp[base + i], v2 = rp[base + 32 + i];
        rp[base + i]      = v1 * cs.x - v2 * cs.y;
        rp[base + 32 + i] = v1 * cs.y + v2 * cs.x;
    }
}

// ---------------------------------------------------------------------------
// table-based rope (replaces powf/sincosf with 1 float2 load)
__global__ void rope_tab(float* __restrict__ buf, int nrows, int rstride,
                         int nheads, int hstride, int roff, int posmod,
                         const float2* __restrict__ tab) {
    int total = nrows * nheads * 32;
    for (int it = blockIdx.x * blockDim.x + threadIdx.x; it < total;
         it += gridDim.x * blockDim.x) {
        int i = it & 31;
        int hr = it >> 5;
        int h = hr % nheads;
        int row = hr / nheads;
        int pos = row % posmod;
        float2 cs = tab[pos * 32 + i];
        size_t base = (size_t)row * rstride + (size_t)h * hstride + roff;
        float v1 = buf[base + i], v2 = buf[base + 32 + i];
        buf[base + i]      = v1 * cs.x - v2 * cs.y;
        buf[base + 32 + i] = v1 * cs.y + v2 * cs.x;
    }
}

// ---------------------------------------------------------------------------
// merged gate softmax + top-k over XW columns; grid = BATCH, 1024 threads
__global__ void topk_gate(const float* __restrict__ xw, int* __restrict__ idx,
                          float* __restrict__ gate) {
    int b = blockIdx.x;
    __shared__ float s[1024];
    __shared__ int ps[1024];
    __shared__ float gred[3][16];
    int t = threadIdx.x;
    const float* rowp = &xw[((size_t)b * T_SEQ + t) * XWW];
    s[t] = rowp[C_IMP];
    // gate partials: thread t holds row t's 3 gate values
    float g0 = rowp[C_GATE + 0], g1 = rowp[C_GATE + 1], g2 = rowp[C_GATE + 2];
    for (int off = 32; off; off >>= 1) {
        g0 += __shfl_xor(g0, off, 64);
        g1 += __shfl_xor(g1, off, 64);
        g2 += __shfl_xor(g2, off, 64);
    }
    if ((t & 63) == 0) { int w = t >> 6; gred[0][w] = g0; gred[1][w] = g1; gred[2][w] = g2; }
    __syncthreads();
    if (t == 0) {
        float v0 = 0.f, v1 = 0.f, v2 = 0.f;
        for (int w = 0; w < 16; w++) { v0 += gred[0][w]; v1 += gred[1][w]; v2 += gred[2][w]; }
        v0 /= (float)T_SEQ; v1 /= (float)T_SEQ; v2 /= (float)T_SEQ;
        float m = fmaxf(v0, fmaxf(v1, v2));
        float e0 = expf(v0 - m), e1 = expf(v1 - m), e2 = expf(v2 - m);
        float ssum = e0 + e1 + e2;
        gate[b * 3 + 0] = e0 / ssum;
        gate[b * 3 + 1] = e1 / ssum;
        gate[b * 3 + 2] = e2 / ssum;
    }
    __syncthreads();
    float mine = s[t];
    int rank = 0;
    for (int j = 0; j < 1024; j++) {
        float v = s[j];
        rank += (v > mine) || (v == mine && j < t);
    }
    int selv = (rank < KEEP) ? 1 : 0;
    ps[t] = selv;
    __syncthreads();
    for (int off = 1; off < 1024; off <<= 1) {
        int add = (t >= off) ? ps[t - off] : 0;
        __syncthreads();
        ps[t] += add;
        __syncthreads();
    }
    if (selv) idx[b * KEEP + ps[t] - 1] = t;
}

__global__ void gather_sel(const float* __restrict__ x, const int* __restrict__ idx,
                           float* __restrict__ sel) {
    for (size_t i = (size_t)blockIdx.x * blockDim.x + threadIdx.x;
         i < (size_t)BATCH * KEEP * CDIM; i += (size_t)gridDim.x * blockDim.x) {
        int c = (int)(i & (CDIM - 1));
        int r = (int)((i >> 10) & (KEEP - 1));
        int b = (int)(i >> 18);
        sel[i] = x[((size_t)b * T_SEQ + idx[b * KEEP + r]) * CDIM + c];
    }
}

// ---------------------------------------------------------------------------
// Fused 3-branch flash attention v5 (measured: 388 us, 0 bank conflicts,
// LDS-pipe + VALU dual-bound). Register-resident online softmax; 2 barriers
// per tile. Grid: (T/64, NHEAD, BATCH), 512 threads. LDS 77.3 KB.
// ---------------------------------------------------------------------------
__global__ __launch_bounds__(512, 4) void flash_fused(
    const float* __restrict__ qkv, const float* __restrict__ xw,
    const float* __restrict__ skv, const float* __restrict__ gate,
    float* __restrict__ out) {
    __shared__ float Qs[BQ * SK];
    __shared__ float Ks[BKT * SK];
    __shared__ float Vs[BKT * SPV];
    __shared__ float Pt[BKT * SPT];

    int b = blockIdx.z, h = blockIdx.y;
    int qt = blockIdx.x;
    if (b == 1) qt = (gridDim.x - 1) - qt;   // balance causal cost across z-pairs
    int q0 = qt * BQ;
    int t = threadIdx.x;
    int tq = t >> 4, tk = t & 15;   // S: q=2*tq+i, k=16*j+tk; PV: q=2*tq+i, d=2*tk+j

    // stage Q tile (64 rows x 24 float4)
    for (int i = t; i < BQ * 24; i += 512) {
        int row = i / 24, d4 = i % 24;
        size_t rq = (size_t)b * T_SEQ + q0 + row;
        float4 v;
        if (d4 < 8) v = *(const float4*)&qkv[rq * QKVW + C_QN + h * 32 + d4 * 4];
        else        v = *(const float4*)&qkv[rq * QKVW + C_QR + h * 64 + (d4 - 8) * 4];
        *(float4*)&Qs[row * SK + d4 * 4] = v;
    }

    int qq0 = q0 + 2 * tq, qq1 = qq0 + 1;
    float comb[2][2] = {};
    for (int phase = 0; phase < 3; phase++) {
        bool causal = (phase != 1);
        int ntiles = causal ? (qt + 1) : (KEEP / BKT);
        float m0 = -1e30f, m1 = -1e30f, l0 = 0.f, l1 = 0.f;
        float o00 = 0.f, o01 = 0.f, o10 = 0.f, o11 = 0.f;

        for (int kt = 0; kt < ntiles; kt++) {
            int j0 = kt * BKT;
            __syncthreads();  // all waves done reading Ks/Vs of prev tile (covers Qs 1st time)

            // stage K tile (64 rows x 24 float4)
            for (int i = t; i < BKT * 24; i += 512) {
                int row = i / 24, d4 = i % 24;
                int j = j0 + row;
                float4 v;
                if (phase == 0) {
                    size_t rk = (size_t)b * T_SEQ + j;
                    if (d4 < 8) v = *(const float4*)&qkv[rk * QKVW + C_KN + h * 32 + d4 * 4];
                    else        v = *(const float4*)&xw[rk * XWW + C_KRO + (d4 - 8) * 4];
                } else if (phase == 1) {
                    v = *(const float4*)&skv[((size_t)b * KEEP + j) * SKW + h * 96 + d4 * 4];
                } else {
                    v = *(const float4*)&xw[((size_t)b * T_SEQ + j) * XWW + C_WINK + h * 96 + d4 * 4];
                }
                *(float4*)&Ks[row * SK + d4 * 4] = v;
            }
            // stage V tile (64 rows x 8 float4)
            for (int i = t; i < BKT * 8; i += 512) {
                int row = i >> 3, d4 = i & 7;
                int j = j0 + row;
                float4 v;
                if (phase == 0)      v = *(const float4*)&qkv[((size_t)b * T_SEQ + j) * QKVW + C_V1 + h * 32 + d4 * 4];
                else if (phase == 1) v = *(const float4*)&skv[((size_t)b * KEEP  + j) * SKW + 1536 + h * 32 + d4 * 4];
                else                 v = *(const float4*)&xw[((size_t)b * T_SEQ + j) * XWW + C_WINV + h * 32 + d4 * 4];
                *(float4*)&Vs[row * SPV + d4 * 4] = v;
            }
            __syncthreads();

            // S = Q.K^T (2q x 4k per thread), registers
            float s0[4] = {}, s1[4] = {};
#pragma unroll 6
            for (int d = 0; d < HEAD_D; d += 4) {
                float4 qa = *(float4*)&Qs[(2 * tq)     * SK + d];
                float4 qb = *(float4*)&Qs[(2 * tq + 1) * SK + d];
#pragma unroll
                for (int j = 0; j < 4; j++) {
                    float4 kv = *(float4*)&Ks[(16 * j + tk) * SK + d];
                    s0[j] += qa.x * kv.x + qa.y * kv.y + qa.z * kv.z + qa.w * kv.w;
                    s1[j] += qb.x * kv.x + qb.y * kv.y + qb.z * kv.z + qb.w * kv.w;
                }
            }
            // scale + mask + tile row-max (in-reg + 4-shfl over 16-lane group)
            float mt0 = -1e30f, mt1 = -1e30f;
#pragma unroll
            for (int j = 0; j < 4; j++) {
                int kk = j0 + 16 * j + tk;
                s0[j] *= SCALE_ATTN;
                s1[j] *= SCALE_ATTN;
                if (causal && kk > qq0) s0[j] = -1e30f;
                if (causal && kk > qq1) s1[j] = -1e30f;
                mt0 = fmaxf(mt0, s0[j]);
                mt1 = fmaxf(mt1, s1[j]);
            }
#pragma unroll
            for (int off = 1; off <= 8; off <<= 1) {
                mt0 = fmaxf(mt0, __shfl_xor(mt0, off, 64));
                mt1 = fmaxf(mt1, __shfl_xor(mt1, off, 64));
            }
            float mn0 = fmaxf(m0, mt0), mn1 = fmaxf(m1, mt1);
            float a0 = __expf(m0 - mn0), a1 = __expf(m1 - mn1);
            m0 = mn0; m1 = mn1;

            // exponentiate in regs, write P once (float2), row-sum via shfl
            float rs0 = 0.f, rs1 = 0.f;
#pragma unroll
            for (int j = 0; j < 4; j++) {
                float p0 = __expf(s0[j] - mn0);
                float p1 = __expf(s1[j] - mn1);
                rs0 += p0; rs1 += p1;
                *(float2*)&Pt[(16 * j + tk) * SPT + 2 * tq] = make_float2(p0, p1);
            }
#pragma unroll
            for (int off = 1; off <= 8; off <<= 1) {
                rs0 += __shfl_xor(rs0, off, 64);
                rs1 += __shfl_xor(rs1, off, 64);
            }
            l0 = l0 * a0 + rs0;
            l1 = l1 * a1 + rs1;

            // PV (2q x 2d). Pt cols 2tq,2tq+1 written by this same wave ->
            // DS in-order per wave, no barrier.
            o00 *= a0; o01 *= a0; o10 *= a1; o11 *= a1;
#pragma unroll 8
            for (int kk = 0; kk < BKT; kk++) {
                float2 pv = *(float2*)&Pt[kk * SPT + 2 * tq];
                float2 vv = *(float2*)&Vs[kk * SPV + 2 * tk];
                o00 += pv.x * vv.x; o01 += pv.x * vv.y;
                o10 += pv.y * vv.x; o11 += pv.y * vv.y;
            }
        }  // key tiles

        // gate combine (m,l in registers, replicated within the group)
        float g = gate[b * 3 + phase];
        float i0 = g / l0, i1 = g / l1;
        comb[0][0] += o00 * i0; comb[0][1] += o01 * i0;
        comb[1][0] += o10 * i1; comb[1][1] += o11 * i1;
    }  // phases

    size_t r0 = ((size_t)b * T_SEQ + q0 + 2 * tq) * 512 + h * 32 + 2 * tk;
    out[r0]           = comb[0][0];
    out[r0 + 1]       = comb[0][1];
    out[r0 + 512]     = comb[1][0];
    out[r0 + 512 + 1] = comb[1][1];
}

// ---------------------------------------------------------------------------
extern "C" void kernel_launch(void* const* d_in, const int* in_sizes, int n_in,
                              void* d_out, int out_size, void* d_ws, size_t ws_size,
                              hipStream_t stream) {
    const float* x        = (const float*)d_in[0];
    const float* w_cq     = (const float*)d_in[1];
    const float* g_qnorm  = (const float*)d_in[2];
    const float* w_dqn    = (const float*)d_in[3];
    const float* w_dqr    = (const float*)d_in[4];
    const float* w_ckv    = (const float*)d_in[5];
    const float* g_kvnorm = (const float*)d_in[6];
    const float* w_dkn    = (const float*)d_in[7];
    const float* w_dv     = (const float*)d_in[8];
    const float* w_krope  = (const float*)d_in[9];
    const float* w_imp    = (const float*)d_in[10];
    const float* w_selk   = (const float*)d_in[11];
    const float* w_selv   = (const float*)d_in[12];
    const float* w_wink   = (const float*)d_in[13];
    const float* w_winv   = (const float*)d_in[14];
    const float* w_gate   = (const float*)d_in[15];
    const float* w_proj   = (const float*)d_in[16];
    float* out = (float*)d_out;

    const int BT = BATCH * T_SEQ;  // 2048
    const int BS = BATCH * KEEP;   // 512

    float* ws = (float*)d_ws;
    size_t o = 0;
    float* XW     = ws + o; o += (size_t)BT * XWW;     // 18.4 MB
    float* QKV    = ws + o; o += (size_t)BT * QKVW;    // 21.0 MB
    float* skv    = ws + o; o += (size_t)BS * SKW;
    float* selb   = ws + o; o += (size_t)BS * CDIM;
    float* attn   = ws + o; o += (size_t)BT * 512;
    float* Bxw    = ws + o; o += (size_t)CDIM * XWW;   // 9.2 MB
    float* Bqkv   = ws + o; o += (size_t)128 * QKVW;
    float* Bsel   = ws + o; o += (size_t)CDIM * SKW;   // 8.4 MB
    float2* tab   = (float2*)(ws + o); o += (size_t)T_SEQ * 32 * 2;  // 256 KB
    float* gatef  = ws + o; o += 8;
    int*   idx    = (int*)(ws + o); o += 512;

    auto gemm = [&](const float* A, const float* Bm, float* C, int M, int N, int K,
                    int lda, int ldb, int ldc, int ksplit = 1) {
        int kchunk = (K / ksplit + GBK - 1) / GBK * GBK;  // %16==0
        dim3 grid((N + 127) / 128, (M + 127) / 128, ksplit);
        gemm128<<<grid, 256, 0, stream>>>(A, Bm, C, M, N, K, lda, ldb, ldc, kchunk);
    };

    // zero split-K destinations (atomicAdd accumulation)
    hipMemsetAsync(skv, 0, (size_t)BS * SKW * sizeof(float), stream);
    hipMemsetAsync(out, 0, (size_t)BT * CDIM * sizeof(float), stream);

    // packs + rope table (independent of GEMM1)
    pack_all<<<2176, 256, 0, stream>>>(Bxw, Bqkv, Bsel,
                                       w_cq, w_ckv, w_krope, w_wink, w_winv,
                                       w_imp, w_gate,
                                       w_dqn, w_dqr, w_dkn, w_dv, w_selk, w_selv);
    build_tab<<<64, 512, 0, stream>>>(tab);

    // GEMM1: everything off x in one wide launch (grid 18x16 = 288)
    gemm(x, Bxw, XW, BT, XWW, CDIM, CDIM, XWW, XWW);

    // fused post pass: rms(cq), rms(ckv), rope(kro), rope(wink)
    xw_post<<<BT, 256, 0, stream>>>(XW, g_qnorm, g_kvnorm, tab);

    // gate + topk merged, then gather
    topk_gate<<<BATCH, 1024, 0, stream>>>(XW, idx, gatef);
    gather_sel<<<2048, 256, 0, stream>>>(x, idx, selb);

    // GEMM2: QKV = [nq|ckv] @ blockdiag (grid 20x16 = 320, K=128)
    gemm(XW, Bqkv, QKV, BT, QKVW, 128, XWW, QKVW, QKVW);
    rope_tab<<<2048, 256, 0, stream>>>(QKV, BT, QKVW, 16, 64, C_QR, T_SEQ, tab);

    // GEMM3: skv = sel @ [w_selk | w_selv], split-K 4-way (grid 16x4x4 = 256)
    gemm(selb, Bsel, skv, BS, SKW, CDIM, CDIM, SKW, SKW, 4);
    rope_tab<<<512, 256, 0, stream>>>(skv, BS, SKW, 16, 96, 32, KEEP, tab);

    // fused attention
    dim3 fgrid(T_SEQ / BQ, NHEAD, BATCH);
    flash_fused<<<fgrid, 512, 0, stream>>>(QKV, XW, skv, gatef, attn);

    // output projection, split-K 2-way (grid 8x16x2 = 256)
    gemm(attn, w_proj, out, BT, CDIM, 512, 512, CDIM, CDIM, 2);
}